// Round 1
// baseline (20222.504 us; speedup 1.0000x reference)
//
#include <hip/hip_runtime.h>
#include <hip/hip_bf16.h>
#include <math.h>

#define B_ 32
#define S_ 128
#define H_ 1024
#define V_ 32000
#define T_ 100
#define L_ 4
#define SPLIT 8   // split-K for GRU GEMMs

// ---------------------------------------------------------------------------
// Embedding precompute: E[t][b][h] = relu(emb[token(t,b)][h])
// token(0,b)=0 ; token(t,b)=target[b][t-1]
// ---------------------------------------------------------------------------
__global__ __launch_bounds__(256) void embed_kernel(
    const int* __restrict__ target, const float* __restrict__ emb,
    float* __restrict__ E)
{
    int bid = blockIdx.x;            // t*B_ + b
    int t = bid / B_, b = bid % B_;
    int tok = (t == 0) ? 0 : target[b * T_ + (t - 1)];
    const float4* src = (const float4*)(emb + (size_t)tok * H_);
    float4* dst = (float4*)(E + ((size_t)t * B_ + b) * H_);
    float4 v = src[threadIdx.x];     // H_/4 == 256 exactly
    v.x = fmaxf(v.x, 0.f); v.y = fmaxf(v.y, 0.f);
    v.z = fmaxf(v.z, 0.f); v.w = fmaxf(v.w, 0.f);
    dst[threadIdx.x] = v;
}

// ---------------------------------------------------------------------------
// L1h[b][g] = sum_h l1_w[g][H_+h] * enc_h[b][h]   (step-invariant)
// ---------------------------------------------------------------------------
__global__ __launch_bounds__(64) void l1h_kernel(
    const float* __restrict__ l1_w, const float* __restrict__ enc_h,
    float* __restrict__ L1h)
{
    int p = blockIdx.x;              // b*3 + g
    int b = p / 3, g = p % 3;
    float s = 0.f;
    for (int h = threadIdx.x; h < H_; h += 64)
        s += l1_w[g * 2 * H_ + H_ + h] * enc_h[b * H_ + h];
    for (int o = 32; o > 0; o >>= 1) s += __shfl_down(s, o);
    if (threadIdx.x == 0) L1h[p] = s;
}

// ---------------------------------------------------------------------------
// Attention (single block): M1 = l1_w[:, :H] @ hidden[0][B-1];
// s_b = l2 . (M1 + L1h[b] + l1_b) + l2_b ; scores = softmax_b(s) ;
// C[h] = sum_b scores[b]*enc_h[b][h]
// ---------------------------------------------------------------------------
__global__ __launch_bounds__(256) void attn_kernel(
    const float* __restrict__ hidden,      // [L][B][H], uses layer 0
    const float* __restrict__ enc_h,       // [B][H]
    const float* __restrict__ L1h,         // [B][3]
    const float* __restrict__ l1_w,        // [3][2H]
    const float* __restrict__ l1_b,        // [3]
    const float* __restrict__ l2_w,        // [3]
    const float* __restrict__ l2_b,        // [1]
    float* __restrict__ Cout,              // [H]
    float* __restrict__ scores_out)        // [B]
{
    __shared__ float red[256];
    __shared__ float sM1[3];
    __shared__ float sSc[B_];
    int tid = threadIdx.x;
    const float* h0last = hidden + (size_t)(B_ - 1) * H_;

    for (int g = 0; g < 3; ++g) {
        float p = 0.f;
        for (int h = tid; h < H_; h += 256)
            p += l1_w[g * 2 * H_ + h] * h0last[h];
        red[tid] = p; __syncthreads();
        for (int s = 128; s > 0; s >>= 1) {
            if (tid < s) red[tid] += red[tid + s];
            __syncthreads();
        }
        if (tid == 0) sM1[g] = red[0];
        __syncthreads();
    }
    if (tid < B_) {
        float sb = l2_b[0];
        for (int g = 0; g < 3; ++g)
            sb += l2_w[g] * (sM1[g] + L1h[tid * 3 + g] + l1_b[g]);
        sSc[tid] = sb;
    }
    __syncthreads();
    if (tid == 0) {
        float m = sSc[0];
        for (int b = 1; b < B_; ++b) m = fmaxf(m, sSc[b]);
        float s = 0.f;
        for (int b = 0; b < B_; ++b) { float e = expf(sSc[b] - m); sSc[b] = e; s += e; }
        float inv = 1.f / s;
        for (int b = 0; b < B_; ++b) { sSc[b] *= inv; scores_out[b] = sSc[b]; }
    }
    __syncthreads();
    for (int h = tid; h < H_; h += 256) {
        float c = 0.f;
        #pragma unroll
        for (int b = 0; b < B_; ++b) c += sSc[b] * enc_h[b * H_ + h];
        Cout[h] = c;
    }
}

// ---------------------------------------------------------------------------
// Skinny GEMM:  out[n][b] (partials) = sum_k W[n][k] * A[b][k]
//   - gridDim.y==2 selects matrix set 1 (W1,A1,K1 -> out1) or 2 (W2,A2,K2 -> out2)
//   - aMode1==1: A row b is  (k<H ? E_t[b][k] : C[k-H])  (layer-0 x)
//   - outMode==0: write partial [ks][b][N]
//   - outMode==1: (S must be 1) write dout[b*T*V + t*V + n] = acc + bias[n]
// Tiling: 128 rows x 64 k per LDS tile, 256 threads, 4x4 accum per thread.
// ---------------------------------------------------------------------------
__global__ __launch_bounds__(256) void skinny_gemm(
    const float* __restrict__ W1, const float* __restrict__ A1, int K1,
    int aMode1, const float* __restrict__ C1,
    const float* __restrict__ W2, const float* __restrict__ A2, int K2,
    float* __restrict__ out1, float* __restrict__ out2,
    int N, int S, int outMode,
    const float* __restrict__ bias, float* __restrict__ dout, int t)
{
    __shared__ float WT[64][132];   // [k][n] transposed W tile (+pad, 16B-aligned rows)
    __shared__ float XT[64][36];    // [k][b] transposed A tile

    const float* W; const float* A; int K; int aMode; const float* Cp; float* outP;
    if (blockIdx.y == 0) { W = W1; A = A1; K = K1; aMode = aMode1; Cp = C1; outP = out1; }
    else                 { W = W2; A = A2; K = K2; aMode = 0;      Cp = nullptr; outP = out2; }

    int ntiles = N >> 7;                  // N/128
    int nt = blockIdx.x % ntiles;
    int ks = blockIdx.x / ntiles;
    int n0 = nt << 7;
    int kslice = K / S;
    int kbeg = ks * kslice, kend = kbeg + kslice;

    int tid = threadIdx.x;
    int ty = tid & 31;        // n = n0 + 4*ty .. +3
    int tx = tid >> 5;        // b = 4*tx .. +3

    float acc[4][4];
    #pragma unroll
    for (int i = 0; i < 4; ++i)
        #pragma unroll
        for (int j = 0; j < 4; ++j) acc[i][j] = 0.f;

    for (int k0 = kbeg; k0 < kend; k0 += 64) {
        // ---- stage W tile (128 rows x 64 cols), transposed into WT[k][n]
        {
            int c = (tid & 15) * 4;       // 0..60
            int rb = tid >> 4;            // 0..15
            #pragma unroll
            for (int i = 0; i < 8; ++i) {
                int r = rb + 16 * i;
                float4 w = *(const float4*)&W[(size_t)(n0 + r) * K + k0 + c];
                WT[c + 0][r] = w.x; WT[c + 1][r] = w.y;
                WT[c + 2][r] = w.z; WT[c + 3][r] = w.w;
            }
        }
        // ---- stage A tile (32 rows x 64 cols), transposed into XT[k][b]
        {
            int b = tid >> 3;             // 0..31
            int cc = (tid & 7) * 8;       // 0..56
            int k = k0 + cc;
            float4 x0, x1;
            if (aMode == 1) {
                if (k < H_) {
                    x0 = *(const float4*)&A[(size_t)b * H_ + k];
                    x1 = *(const float4*)&A[(size_t)b * H_ + k + 4];
                } else {
                    x0 = *(const float4*)&Cp[k - H_];
                    x1 = *(const float4*)&Cp[k - H_ + 4];
                }
            } else {
                x0 = *(const float4*)&A[(size_t)b * K + k];
                x1 = *(const float4*)&A[(size_t)b * K + k + 4];
            }
            XT[cc + 0][b] = x0.x; XT[cc + 1][b] = x0.y;
            XT[cc + 2][b] = x0.z; XT[cc + 3][b] = x0.w;
            XT[cc + 4][b] = x1.x; XT[cc + 5][b] = x1.y;
            XT[cc + 6][b] = x1.z; XT[cc + 7][b] = x1.w;
        }
        __syncthreads();
        #pragma unroll 16
        for (int kk = 0; kk < 64; ++kk) {
            float4 wv = *(const float4*)&WT[kk][4 * ty];
            float4 xv = *(const float4*)&XT[kk][4 * tx];
            acc[0][0] += wv.x * xv.x; acc[0][1] += wv.x * xv.y;
            acc[0][2] += wv.x * xv.z; acc[0][3] += wv.x * xv.w;
            acc[1][0] += wv.y * xv.x; acc[1][1] += wv.y * xv.y;
            acc[1][2] += wv.y * xv.z; acc[1][3] += wv.y * xv.w;
            acc[2][0] += wv.z * xv.x; acc[2][1] += wv.z * xv.y;
            acc[2][2] += wv.z * xv.z; acc[2][3] += wv.z * xv.w;
            acc[3][0] += wv.w * xv.x; acc[3][1] += wv.w * xv.y;
            acc[3][2] += wv.w * xv.z; acc[3][3] += wv.w * xv.w;
        }
        __syncthreads();
    }

    int n = n0 + 4 * ty;
    if (outMode == 0) {
        float* o = outP + (size_t)ks * B_ * N;
        #pragma unroll
        for (int j = 0; j < 4; ++j) {
            int b = 4 * tx + j;
            float4 v = make_float4(acc[0][j], acc[1][j], acc[2][j], acc[3][j]);
            *(float4*)&o[(size_t)b * N + n] = v;
        }
    } else {
        float4 bb = *(const float4*)&bias[n];
        #pragma unroll
        for (int j = 0; j < 4; ++j) {
            int b = 4 * tx + j;
            float4 v = make_float4(acc[0][j] + bb.x, acc[1][j] + bb.y,
                                   acc[2][j] + bb.z, acc[3][j] + bb.w);
            *(float4*)&dout[(size_t)b * T_ * V_ + (size_t)t * V_ + n] = v;
        }
    }
}

// ---------------------------------------------------------------------------
// GRU gate: reduce split-K partials, add biases, gate math, in-place h update
// ---------------------------------------------------------------------------
__global__ __launch_bounds__(256) void gru_gate(
    const float* __restrict__ giP, const float* __restrict__ ghP, int S,
    const float* __restrict__ b_ih, const float* __restrict__ b_hh,
    float* __restrict__ h)            // hidden + l*B*H
{
    int j = blockIdx.x * 256 + threadIdx.x;   // 0..H-1
    int b = blockIdx.y;
    const int N = 3 * H_;
    float ir = b_ih[j], iz = b_ih[H_ + j], in_ = b_ih[2 * H_ + j];
    float hr = b_hh[j], hz = b_hh[H_ + j], hn = b_hh[2 * H_ + j];
    for (int ks = 0; ks < S; ++ks) {
        const float* gi = giP + ((size_t)ks * B_ + b) * N;
        const float* gh = ghP + ((size_t)ks * B_ + b) * N;
        ir += gi[j]; iz += gi[H_ + j]; in_ += gi[2 * H_ + j];
        hr += gh[j]; hz += gh[H_ + j]; hn += gh[2 * H_ + j];
    }
    float r = 1.f / (1.f + expf(-(ir + hr)));
    float z = 1.f / (1.f + expf(-(iz + hz)));
    float n = tanhf(in_ + r * hn);
    float hold = h[(size_t)b * H_ + j];
    h[(size_t)b * H_ + j] = (1.f - z) * n + z * hold;
}

// ---------------------------------------------------------------------------
// In-place log_softmax over rows of V_ in d_out (one block per (b,t) row)
// ---------------------------------------------------------------------------
__global__ __launch_bounds__(256) void logsoftmax_kernel(float* __restrict__ dout)
{
    __shared__ float red[256];
    size_t row = blockIdx.x;
    float* x = dout + row * (size_t)V_;
    int tid = threadIdx.x;

    float m = -INFINITY;
    for (int v = tid; v < V_; v += 256) m = fmaxf(m, x[v]);
    red[tid] = m; __syncthreads();
    for (int s = 128; s > 0; s >>= 1) {
        if (tid < s) red[tid] = fmaxf(red[tid], red[tid + s]);
        __syncthreads();
    }
    m = red[0]; __syncthreads();

    float s = 0.f;
    for (int v = tid; v < V_; v += 256) s += expf(x[v] - m);
    red[tid] = s; __syncthreads();
    for (int ss = 128; ss > 0; ss >>= 1) {
        if (tid < ss) red[tid] += red[tid + ss];
        __syncthreads();
    }
    float lse = m + logf(red[0]);
    __syncthreads();

    for (int v = tid; v < V_; v += 256) x[v] = x[v] - lse;
}

// ---------------------------------------------------------------------------
extern "C" void kernel_launch(void* const* d_in, const int* in_sizes, int n_in,
                              void* d_out, int out_size, void* d_ws, size_t ws_size,
                              hipStream_t stream)
{
    (void)in_sizes; (void)n_in; (void)out_size; (void)ws_size;

    const float* enc_hidden = (const float*)d_in[1];   // [L][B][H]; layer 0 slice = enc_h
    const int*   target     = (const int*)  d_in[2];   // [B][T]
    const float* emb        = (const float*)d_in[3];   // [V][H]
    const float* w_ih0      = (const float*)d_in[4];   // [3H][2H]
    const float* w_hh0      = (const float*)d_in[5];   // [3H][H]
    const float* b_ih0      = (const float*)d_in[6];
    const float* b_hh0      = (const float*)d_in[7];
    const float* w_ih       = (const float*)d_in[8];   // [3][3H][H]
    const float* w_hh       = (const float*)d_in[9];   // [3][3H][H]
    const float* b_ih       = (const float*)d_in[10];  // [3][3H]
    const float* b_hh       = (const float*)d_in[11];  // [3][3H]
    const float* out_w      = (const float*)d_in[12];  // [V][H]
    const float* out_b      = (const float*)d_in[13];  // [V]
    const float* l1_w       = (const float*)d_in[14];  // [3][2H]
    const float* l1_b       = (const float*)d_in[15];
    const float* l2_w       = (const float*)d_in[16];
    const float* l2_b       = (const float*)d_in[17];
    float* out = (float*)d_out;

    // --- workspace carve (all fp32) ---
    char* w = (char*)d_ws;
    float* hidden = (float*)w;                 w += (size_t)L_ * B_ * H_ * 4;       // 512 KB
    float* E      = (float*)w;                 w += (size_t)T_ * B_ * H_ * 4;       // 12.5 MB
    float* Cbuf   = (float*)w;                 w += (size_t)H_ * 4;
    float* scores = (float*)w;                 w += 256;
    float* L1h    = (float*)w;                 w += 1024;
    float* giP    = (float*)w;                 w += (size_t)SPLIT * B_ * 3 * H_ * 4; // 3 MB
    float* ghP    = (float*)w;                 w += (size_t)SPLIT * B_ * 3 * H_ * 4; // 3 MB

    const int N3H = 3 * H_;

    hipMemcpyAsync(hidden, enc_hidden, (size_t)L_ * B_ * H_ * 4,
                   hipMemcpyDeviceToDevice, stream);
    embed_kernel<<<T_ * B_, 256, 0, stream>>>(target, emb, E);
    l1h_kernel<<<B_ * 3, 64, 0, stream>>>(l1_w, enc_hidden, L1h);

    for (int t = 0; t < T_; ++t) {
        attn_kernel<<<1, 256, 0, stream>>>(hidden, enc_hidden, L1h,
                                           l1_w, l1_b, l2_w, l2_b, Cbuf, scores);
        // layer 0: gi = x0 @ w_ih0^T (K=2048, x0 = [E_t | C]),  gh = h0 @ w_hh0^T
        skinny_gemm<<<dim3((N3H >> 7) * SPLIT, 2), 256, 0, stream>>>(
            w_ih0, E + (size_t)t * B_ * H_, 2 * H_, 1, Cbuf,
            w_hh0, hidden, H_,
            giP, ghP, N3H, SPLIT, 0, nullptr, nullptr, 0);
        gru_gate<<<dim3(H_ / 256, B_), 256, 0, stream>>>(giP, ghP, SPLIT,
                                                         b_ih0, b_hh0, hidden);
        for (int l = 1; l < L_; ++l) {
            skinny_gemm<<<dim3((N3H >> 7) * SPLIT, 2), 256, 0, stream>>>(
                w_ih + (size_t)(l - 1) * N3H * H_, hidden + (size_t)(l - 1) * B_ * H_, H_, 0, nullptr,
                w_hh + (size_t)(l - 1) * N3H * H_, hidden + (size_t)l * B_ * H_, H_,
                giP, ghP, N3H, SPLIT, 0, nullptr, nullptr, 0);
            gru_gate<<<dim3(H_ / 256, B_), 256, 0, stream>>>(
                giP, ghP, SPLIT,
                b_ih + (size_t)(l - 1) * N3H, b_hh + (size_t)(l - 1) * N3H,
                hidden + (size_t)l * B_ * H_);
        }
        // logits: direct write into d_out[b][t][v] (+ bias)
        skinny_gemm<<<dim3(V_ >> 7, 1), 256, 0, stream>>>(
            out_w, hidden + (size_t)(L_ - 1) * B_ * H_, H_, 0, nullptr,
            nullptr, nullptr, H_,
            nullptr, nullptr, V_, 1, 1, out_b, out, t);
    }

    logsoftmax_kernel<<<B_ * T_, 256, 0, stream>>>(out);
    hipMemcpyAsync(out + (size_t)B_ * T_ * V_, hidden, (size_t)L_ * B_ * H_ * 4,
                   hipMemcpyDeviceToDevice, stream);
    hipMemcpyAsync(out + (size_t)B_ * T_ * V_ + (size_t)L_ * B_ * H_, scores,
                   B_ * 4, hipMemcpyDeviceToDevice, stream);
}

// Round 2
// 11035.539 us; speedup vs baseline: 1.8325x; 1.8325x over previous
//
#include <hip/hip_runtime.h>
#include <hip/hip_bf16.h>
#include <math.h>

#define B_ 32
#define H_ 1024
#define V_ 32000
#define T_ 100
#define L_ 4
#define TB_ (T_*B_)      // 3200
#define N3H (3*H_)       // 3072

typedef __attribute__((ext_vector_type(8))) short bf16x8;
typedef __attribute__((ext_vector_type(4))) float f32x4;
typedef __attribute__((ext_vector_type(4))) unsigned short u16x4;

__device__ inline unsigned short f2bf(float f) {
    union { float f; unsigned u; } v; v.f = f;
    unsigned r = v.u + 0x7fff + ((v.u >> 16) & 1);   // RNE
    return (unsigned short)(r >> 16);
}
__device__ inline float bf2f(unsigned short u) {
    union { unsigned u; float f; } v; v.u = ((unsigned)u) << 16; return v.f;
}

// ---------------------------------------------------------------------------
// fp32 -> bf16 contiguous convert (n4 = element count / 4)
// ---------------------------------------------------------------------------
__global__ __launch_bounds__(256) void convbf_kernel(
    const float* __restrict__ src, unsigned short* __restrict__ dst, int n4)
{
    for (int i = blockIdx.x * 256 + threadIdx.x; i < n4; i += gridDim.x * 256) {
        float4 v = ((const float4*)src)[i];
        u16x4 o; o.x = f2bf(v.x); o.y = f2bf(v.y); o.z = f2bf(v.z); o.w = f2bf(v.w);
        ((u16x4*)dst)[i] = o;
    }
}

// ---------------------------------------------------------------------------
// Ebf[t*B+b][h] = bf16(relu(emb[token(t,b)][h]))
// ---------------------------------------------------------------------------
__global__ __launch_bounds__(256) void embed_bf_kernel(
    const int* __restrict__ target, const float* __restrict__ emb,
    unsigned short* __restrict__ Ebf)
{
    int bid = blockIdx.x;                  // t*B+b
    int t = bid >> 5, b = bid & 31;
    int tok = (t == 0) ? 0 : target[b * T_ + (t - 1)];
    float4 v = ((const float4*)(emb + (size_t)tok * H_))[threadIdx.x];
    u16x4 o;
    o.x = f2bf(fmaxf(v.x, 0.f)); o.y = f2bf(fmaxf(v.y, 0.f));
    o.z = f2bf(fmaxf(v.z, 0.f)); o.w = f2bf(fmaxf(v.w, 0.f));
    ((u16x4*)(Ebf + (size_t)bid * H_))[threadIdx.x] = o;
}

// ---------------------------------------------------------------------------
// Attention collapse (step-invariant): scores = softmax_b(c_b), C = sum scores*enc_h
// ---------------------------------------------------------------------------
__global__ __launch_bounds__(256) void attn_pre_kernel(
    const float* __restrict__ enc_h, const float* __restrict__ l1_w,
    const float* __restrict__ l1_b, const float* __restrict__ l2_w,
    float* __restrict__ Cout, float* __restrict__ scores)
{
    __shared__ float L1h[96];
    __shared__ float sc[32];
    int tid = threadIdx.x, wv = tid >> 6, lane = tid & 63;
    for (int d = wv; d < 96; d += 4) {
        int b = d / 3, g = d - 3 * b;
        const float4* wp = (const float4*)(l1_w + (size_t)g * 2 * H_ + H_);
        const float4* ep = (const float4*)(enc_h + (size_t)b * H_);
        float s = 0.f;
        for (int q = lane; q < 256; q += 64) {
            float4 w4 = wp[q], e4 = ep[q];
            s += w4.x * e4.x + w4.y * e4.y + w4.z * e4.z + w4.w * e4.w;
        }
        for (int o = 32; o > 0; o >>= 1) s += __shfl_down(s, o);
        if (lane == 0) L1h[d] = s;
    }
    __syncthreads();
    if (tid < 32) {
        float cb = 0.f;
        for (int g = 0; g < 3; ++g) cb += l2_w[g] * (L1h[tid * 3 + g] + l1_b[g]);
        sc[tid] = cb;
    }
    __syncthreads();
    if (tid == 0) {
        float m = sc[0];
        for (int b = 1; b < 32; ++b) m = fmaxf(m, sc[b]);
        float s = 0.f;
        for (int b = 0; b < 32; ++b) { float e = expf(sc[b] - m); sc[b] = e; s += e; }
        float inv = 1.f / s;
        for (int b = 0; b < 32; ++b) { sc[b] *= inv; scores[b] = sc[b]; }
    }
    __syncthreads();
    float4 c = make_float4(0.f, 0.f, 0.f, 0.f);
    for (int b = 0; b < 32; ++b) {
        float4 e = ((const float4*)(enc_h + (size_t)b * H_))[tid];
        float ww = sc[b];
        c.x += ww * e.x; c.y += ww * e.y; c.z += ww * e.z; c.w += ww * e.w;
    }
    ((float4*)Cout)[tid] = c;
}

// ---------------------------------------------------------------------------
// wcC[n] = sum_k w_ih0[n][H+k] * C[k]   (constant layer-0 context term)
// ---------------------------------------------------------------------------
__global__ __launch_bounds__(256) void wcc_kernel(
    const float* __restrict__ w_ih0, const float* __restrict__ C,
    float* __restrict__ wcC)
{
    int row = blockIdx.x * 4 + (threadIdx.x >> 6);
    int lane = threadIdx.x & 63;
    const float4* wp = (const float4*)(w_ih0 + (size_t)row * 2 * H_ + H_);
    const float4* cp = (const float4*)C;
    float s = 0.f;
    for (int q = lane; q < 256; q += 64) {
        float4 w4 = wp[q], c4 = cp[q];
        s += w4.x * c4.x + w4.y * c4.y + w4.z * c4.z + w4.w * c4.w;
    }
    for (int o = 32; o > 0; o >>= 1) s += __shfl_down(s, o);
    if (lane == 0) wcC[row] = s;
}

// ---------------------------------------------------------------------------
// Big MFMA GEMM: out[row][col] = sum_k A[row][k]*Bb[col][k] + bias[row]
//   A fp32 (abf=0, on-the-fly cvt) or bf16 (abf=1), row-major with stride lda
//   Bb bf16 [col][1024]
//   outMode 0: bf16 out[col*M + row]   (G0)
//   outMode 1: fp32 dout[b*T*V + t*V + row], col = t*32+b   (logits)
// Grid: (M/128, cols/128), 256 threads = 4 waves, wave = 64 rows x 64 cols
// ---------------------------------------------------------------------------
__global__ __launch_bounds__(256) void big_gemm_kernel(
    const void* __restrict__ Aptr, int lda, int abf,
    const unsigned short* __restrict__ Bb,
    const float* __restrict__ bias, int M, int outMode,
    void* __restrict__ outp)
{
    int tid = threadIdx.x, wv = tid >> 6, lane = tid & 63;
    int rlo = lane & 15, klane = (lane >> 4) * 8;
    int rowB = blockIdx.x * 128 + (wv >> 1) * 64;
    int colB = blockIdx.y * 128 + (wv & 1) * 64;
    const unsigned short* Ab = (const unsigned short*)Aptr;
    const float* Af = (const float*)Aptr;

    f32x4 acc[4][4];
    #pragma unroll
    for (int i = 0; i < 4; ++i)
        #pragma unroll
        for (int j = 0; j < 4; ++j) acc[i][j] = (f32x4){0.f, 0.f, 0.f, 0.f};

    for (int k0 = 0; k0 < H_; k0 += 32) {
        bf16x8 bfrag[4];
        #pragma unroll
        for (int ci = 0; ci < 4; ++ci) {
            int col = colB + ci * 16 + rlo;
            bfrag[ci] = *(const bf16x8*)(Bb + (size_t)col * H_ + k0 + klane);
        }
        #pragma unroll
        for (int ri = 0; ri < 4; ++ri) {
            int row = rowB + ri * 16 + rlo;
            bf16x8 af;
            if (abf) {
                af = *(const bf16x8*)(Ab + (size_t)row * lda + k0 + klane);
            } else {
                const float* ap = Af + (size_t)row * lda + k0 + klane;
                float4 x0 = *(const float4*)ap, x1 = *(const float4*)(ap + 4);
                af[0] = (short)f2bf(x0.x); af[1] = (short)f2bf(x0.y);
                af[2] = (short)f2bf(x0.z); af[3] = (short)f2bf(x0.w);
                af[4] = (short)f2bf(x1.x); af[5] = (short)f2bf(x1.y);
                af[6] = (short)f2bf(x1.z); af[7] = (short)f2bf(x1.w);
            }
            #pragma unroll
            for (int ci = 0; ci < 4; ++ci)
                acc[ri][ci] = __builtin_amdgcn_mfma_f32_16x16x32_bf16(
                    af, bfrag[ci], acc[ri][ci], 0, 0, 0);
        }
    }

    int rowoff = (lane >> 4) * 4;
    #pragma unroll
    for (int ri = 0; ri < 4; ++ri) {
        int row = rowB + ri * 16 + rowoff;
        float4 bs = *(const float4*)(bias + row);
        #pragma unroll
        for (int ci = 0; ci < 4; ++ci) {
            int col = colB + ci * 16 + rlo;
            float4 v;
            v.x = acc[ri][ci][0] + bs.x; v.y = acc[ri][ci][1] + bs.y;
            v.z = acc[ri][ci][2] + bs.z; v.w = acc[ri][ci][3] + bs.w;
            if (outMode == 1) {
                int tt = col >> 5, b = col & 31;
                *(float4*)((float*)outp + ((size_t)b * T_ + tt) * V_ + row) = v;
            } else {
                u16x4 o; o.x = f2bf(v.x); o.y = f2bf(v.y);
                o.z = f2bf(v.z); o.w = f2bf(v.w);
                *(u16x4*)((unsigned short*)outp + (size_t)col * M + row) = o;
            }
        }
    }
}

// ---------------------------------------------------------------------------
// Fused per-layer GRU: dual skinny GEMM (MFMA) + gate math epilogue.
// mode 0 (layer 0): F=32 features/block, gh only (gi read from G0), grid 32
// mode 1 (layers 1-3): F=16 features/block, gi+gh, grid 64
// 512 threads = 8 waves: wq=wv&3 picks 3 of 12 (ntile,btile) pairs,
// kh=wv>>2 picks K half; partial sums combined through LDS in epilogue.
// ---------------------------------------------------------------------------
__global__ __launch_bounds__(512) void gru_layer_kernel(
    const unsigned short* __restrict__ Wih,
    const unsigned short* __restrict__ Whh,
    const unsigned short* __restrict__ G0,
    const float* __restrict__ b_ihv, const float* __restrict__ b_hhv,
    const unsigned short* __restrict__ hprev_bf,   // prev layer h (this step)
    const unsigned short* __restrict__ hcur_bf,    // own h (prev step) bf16
    const float* __restrict__ hcur_f32,            // own h (prev step) fp32
    float* __restrict__ hout_f32,
    unsigned short* __restrict__ hout_bf,
    unsigned short* __restrict__ hist,             // pre-offset by t, or null
    int mode, int t)
{
    __shared__ float sacc[2][96][33];
    int tid = threadIdx.x;
    int wv = tid >> 6, lane = tid & 63;
    int wq = wv & 3, kh = wv >> 2;
    int rlo = lane & 15, klane = (lane >> 4) * 8;
    int F = mode ? 16 : 32;
    int f0 = blockIdx.x * F;

    const unsigned short* wp[3];
    const unsigned short* ap[3];
    int ntv[3], btv[3];
    #pragma unroll
    for (int i = 0; i < 3; ++i) {
        int q = wq * 3 + i;
        int nt = q >> 1; ntv[i] = nt; btv[i] = q & 1;
        int wrow; const unsigned short* Wm; const unsigned short* Am;
        if (mode == 0) {
            int g = nt >> 1, half = nt & 1;
            wrow = g * H_ + f0 + half * 16; Wm = Whh; Am = hcur_bf;
        } else if (nt < 3) {
            wrow = nt * H_ + f0; Wm = Wih; Am = hprev_bf;
        } else {
            wrow = (nt - 3) * H_ + f0; Wm = Whh; Am = hcur_bf;
        }
        wp[i] = Wm + (size_t)(wrow + rlo) * H_ + klane;
        ap[i] = Am + (size_t)(btv[i] * 16 + rlo) * H_ + klane;
    }

    f32x4 acc[3];
    #pragma unroll
    for (int i = 0; i < 3; ++i) acc[i] = (f32x4){0.f, 0.f, 0.f, 0.f};

    int kbeg = kh * 512, kend = kbeg + 512;
    #pragma unroll 2
    for (int k0 = kbeg; k0 < kend; k0 += 32) {
        #pragma unroll
        for (int i = 0; i < 3; ++i) {
            bf16x8 a = *(const bf16x8*)(wp[i] + k0);
            bf16x8 b = *(const bf16x8*)(ap[i] + k0);
            acc[i] = __builtin_amdgcn_mfma_f32_16x16x32_bf16(a, b, acc[i], 0, 0, 0);
        }
    }

    int rowoff = (lane >> 4) * 4;
    #pragma unroll
    for (int i = 0; i < 3; ++i)
        #pragma unroll
        for (int r = 0; r < 4; ++r)
            sacc[kh][ntv[i] * 16 + rowoff + r][btv[i] * 16 + rlo] = acc[i][r];
    __syncthreads();

    if (mode) {
        int f = tid >> 5, b = tid & 31;    // 512 outputs: 16 features x 32 batch
        int j = f0 + f;
        float ir = sacc[0][f][b]      + sacc[1][f][b]      + b_ihv[j];
        float iz = sacc[0][16 + f][b] + sacc[1][16 + f][b] + b_ihv[H_ + j];
        float in_= sacc[0][32 + f][b] + sacc[1][32 + f][b] + b_ihv[2 * H_ + j];
        float hr = sacc[0][48 + f][b] + sacc[1][48 + f][b] + b_hhv[j];
        float hz = sacc[0][64 + f][b] + sacc[1][64 + f][b] + b_hhv[H_ + j];
        float hn = sacc[0][80 + f][b] + sacc[1][80 + f][b] + b_hhv[2 * H_ + j];
        float r = 1.f / (1.f + expf(-(ir + hr)));
        float z = 1.f / (1.f + expf(-(iz + hz)));
        float n = tanhf(in_ + r * hn);
        float hnew = (1.f - z) * n + z * hcur_f32[b * H_ + j];
        hout_f32[b * H_ + j] = hnew;
        unsigned short hb = f2bf(hnew);
        hout_bf[b * H_ + j] = hb;
        if (hist) hist[b * H_ + j] = hb;
    } else {
        #pragma unroll
        for (int rep = 0; rep < 2; ++rep) {
            int idx = rep * 512 + tid;     // 1024 outputs: 32 features x 32 batch
            int fi = idx & 31, b = idx >> 5;
            int j = f0 + fi;
            const unsigned short* g0p = G0 + (size_t)(t * B_ + b) * N3H;
            float ir = bf2f(g0p[j])          + b_ihv[j];
            float iz = bf2f(g0p[H_ + j])     + b_ihv[H_ + j];
            float in_= bf2f(g0p[2 * H_ + j]) + b_ihv[2 * H_ + j];
            float hr = sacc[0][fi][b]      + sacc[1][fi][b]      + b_hhv[j];
            float hz = sacc[0][32 + fi][b] + sacc[1][32 + fi][b] + b_hhv[H_ + j];
            float hn = sacc[0][64 + fi][b] + sacc[1][64 + fi][b] + b_hhv[2 * H_ + j];
            float r = 1.f / (1.f + expf(-(ir + hr)));
            float z = 1.f / (1.f + expf(-(iz + hz)));
            float n = tanhf(in_ + r * hn);
            float hnew = (1.f - z) * n + z * hcur_f32[b * H_ + j];
            hout_f32[b * H_ + j] = hnew;
            hout_bf[b * H_ + j] = f2bf(hnew);
        }
    }
}

// ---------------------------------------------------------------------------
// In-place log_softmax over rows of V_ (float4 vectorized)
// ---------------------------------------------------------------------------
__global__ __launch_bounds__(256) void logsoftmax_kernel(float* __restrict__ dout)
{
    __shared__ float red[256];
    float4* x4 = (float4*)(dout + (size_t)blockIdx.x * V_);
    const int N4 = V_ / 4;
    int tid = threadIdx.x;

    float m = -INFINITY;
    for (int i = tid; i < N4; i += 256) {
        float4 v = x4[i];
        m = fmaxf(m, fmaxf(fmaxf(v.x, v.y), fmaxf(v.z, v.w)));
    }
    red[tid] = m; __syncthreads();
    for (int s = 128; s > 0; s >>= 1) {
        if (tid < s) red[tid] = fmaxf(red[tid], red[tid + s]);
        __syncthreads();
    }
    m = red[0]; __syncthreads();

    float s = 0.f;
    for (int i = tid; i < N4; i += 256) {
        float4 v = x4[i];
        s += expf(v.x - m) + expf(v.y - m) + expf(v.z - m) + expf(v.w - m);
    }
    red[tid] = s; __syncthreads();
    for (int ss = 128; ss > 0; ss >>= 1) {
        if (tid < ss) red[tid] += red[tid + ss];
        __syncthreads();
    }
    float lse = m + logf(red[0]);
    __syncthreads();

    for (int i = tid; i < N4; i += 256) {
        float4 v = x4[i];
        v.x -= lse; v.y -= lse; v.z -= lse; v.w -= lse;
        x4[i] = v;
    }
}

// ---------------------------------------------------------------------------
extern "C" void kernel_launch(void* const* d_in, const int* in_sizes, int n_in,
                              void* d_out, int out_size, void* d_ws, size_t ws_size,
                              hipStream_t stream)
{
    (void)in_sizes; (void)n_in; (void)out_size;

    const float* enc_hidden = (const float*)d_in[1];   // [L][B][H]; layer0 = enc_h
    const int*   target     = (const int*)  d_in[2];   // [B][T]
    const float* emb        = (const float*)d_in[3];   // [V][H]
    const float* w_ih0      = (const float*)d_in[4];   // [3H][2H]
    const float* w_hh0      = (const float*)d_in[5];   // [3H][H]
    const float* b_ih0      = (const float*)d_in[6];
    const float* b_hh0      = (const float*)d_in[7];
    const float* w_ih       = (const float*)d_in[8];   // [3][3H][H]
    const float* w_hh       = (const float*)d_in[9];   // [3][3H][H]
    const float* b_ih       = (const float*)d_in[10];  // [3][3H]
    const float* b_hh       = (const float*)d_in[11];  // [3][3H]
    const float* out_w      = (const float*)d_in[12];  // [V][H]
    const float* out_b      = (const float*)d_in[13];  // [V]
    const float* l1_w       = (const float*)d_in[14];  // [3][2H]
    const float* l1_b       = (const float*)d_in[15];
    const float* l2_w       = (const float*)d_in[16];
    const float* l2_b       = (const float*)d_in[17];
    (void)l2_b;
    float* out = (float*)d_out;

    // --- workspace carve ---
    char* w = (char*)d_ws;
    auto alloc = [&](size_t bytes) -> char* {
        char* p = w; w += (bytes + 255) & ~(size_t)255; return p;
    };
    unsigned short* whh0_bf = (unsigned short*)alloc((size_t)N3H * H_ * 2);
    unsigned short* wih_bf  = (unsigned short*)alloc((size_t)3 * N3H * H_ * 2);
    unsigned short* whh_bf  = (unsigned short*)alloc((size_t)3 * N3H * H_ * 2);
    unsigned short* Ebf     = (unsigned short*)alloc((size_t)TB_ * H_ * 2);
    unsigned short* G0      = (unsigned short*)alloc((size_t)TB_ * N3H * 2);
    unsigned short* Hist    = (unsigned short*)alloc((size_t)TB_ * H_ * 2);
    float*          hf32    = (float*)alloc((size_t)2 * L_ * B_ * H_ * 4);
    unsigned short* hbf     = (unsigned short*)alloc((size_t)2 * L_ * B_ * H_ * 2);
    float*          Cbuf    = (float*)alloc(H_ * 4);
    float*          scores  = (float*)alloc(256);
    float*          wcC     = (float*)alloc(N3H * 4);
    size_t used = (size_t)(w - (char*)d_ws);
    unsigned short* outw_bf = nullptr;
    if (used + (size_t)V_ * H_ * 2 + 256 <= ws_size)
        outw_bf = (unsigned short*)alloc((size_t)V_ * H_ * 2);

    // --- one-time precompute ---
    convbf_kernel<<<512, 256, 0, stream>>>(w_hh0, whh0_bf, N3H * H_ / 4);
    convbf_kernel<<<1024, 256, 0, stream>>>(w_ih, wih_bf, 3 * N3H * H_ / 4);
    convbf_kernel<<<1024, 256, 0, stream>>>(w_hh, whh_bf, 3 * N3H * H_ / 4);
    if (outw_bf)
        convbf_kernel<<<2048, 256, 0, stream>>>(out_w, outw_bf, V_ * H_ / 4);
    embed_bf_kernel<<<TB_, 256, 0, stream>>>(target, emb, Ebf);
    hipMemcpyAsync(hf32, enc_hidden, (size_t)L_ * B_ * H_ * 4,
                   hipMemcpyDeviceToDevice, stream);
    convbf_kernel<<<128, 256, 0, stream>>>(enc_hidden, hbf, L_ * B_ * H_ / 4);
    attn_pre_kernel<<<1, 256, 0, stream>>>(enc_hidden, l1_w, l1_b, l2_w, Cbuf, scores);
    wcc_kernel<<<N3H / 4, 256, 0, stream>>>(w_ih0, Cbuf, wcC);
    // G0 = W_E @ E (+ wcC): A = left half of w_ih0 (fp32, lda=2H)
    big_gemm_kernel<<<dim3(N3H / 128, TB_ / 128), 256, 0, stream>>>(
        w_ih0, 2 * H_, 0, Ebf, wcC, N3H, 0, G0);

    // --- sequential decode: 4 fused layer kernels per step ---
    const size_t LBH = (size_t)L_ * B_ * H_;
    for (int t = 0; t < T_; ++t) {
        int p = t & 1;
        const float* hf_in = hf32 + (size_t)p * LBH;
        float* hf_out = hf32 + (size_t)(1 - p) * LBH;
        const unsigned short* hb_in = hbf + (size_t)p * LBH;
        unsigned short* hb_out = hbf + (size_t)(1 - p) * LBH;

        gru_layer_kernel<<<32, 512, 0, stream>>>(
            nullptr, whh0_bf, G0, b_ih0, b_hh0,
            nullptr, hb_in, hf_in, hf_out, hb_out, nullptr, 0, t);

        for (int l = 1; l < L_; ++l) {
            gru_layer_kernel<<<64, 512, 0, stream>>>(
                wih_bf + (size_t)(l - 1) * N3H * H_,
                whh_bf + (size_t)(l - 1) * N3H * H_, nullptr,
                b_ih + (size_t)(l - 1) * N3H, b_hh + (size_t)(l - 1) * N3H,
                hb_out + (size_t)(l - 1) * B_ * H_,
                hb_in + (size_t)l * B_ * H_,
                hf_in + (size_t)l * B_ * H_,
                hf_out + (size_t)l * B_ * H_,
                hb_out + (size_t)l * B_ * H_,
                (l == L_ - 1) ? Hist + (size_t)t * B_ * H_ : nullptr, 1, t);
        }
    }

    // --- deferred logits GEMM over all (t,b), then log_softmax ---
    if (outw_bf)
        big_gemm_kernel<<<dim3(V_ / 128, TB_ / 128), 256, 0, stream>>>(
            outw_bf, H_, 1, Hist, out_b, V_, 1, out);
    else
        big_gemm_kernel<<<dim3(V_ / 128, TB_ / 128), 256, 0, stream>>>(
            out_w, H_, 0, Hist, out_b, V_, 1, out);
    logsoftmax_kernel<<<TB_, 256, 0, stream>>>(out);

    // --- final hidden (T even -> buffer 0) and constant scores ---
    hipMemcpyAsync(out + (size_t)B_ * T_ * V_, hf32, LBH * 4,
                   hipMemcpyDeviceToDevice, stream);
    hipMemcpyAsync(out + (size_t)B_ * T_ * V_ + LBH, scores, B_ * 4,
                   hipMemcpyDeviceToDevice, stream);
}

// Round 3
// 6698.592 us; speedup vs baseline: 3.0189x; 1.6474x over previous
//
#include <hip/hip_runtime.h>
#include <hip/hip_bf16.h>
#include <math.h>

#define B_ 32
#define H_ 1024
#define V_ 32000
#define T_ 100
#define L_ 4
#define TB_ (T_*B_)      // 3200
#define N3H (3*H_)       // 3072
#define NBLK 224         // decode grid: 32 (layer0) + 3*64 (layers 1-3)
#define L0BLK 32

typedef __attribute__((ext_vector_type(8))) short bf16x8;
typedef __attribute__((ext_vector_type(4))) float f32x4;
typedef __attribute__((ext_vector_type(4))) unsigned short u16x4;

__device__ inline unsigned short f2bf(float f) {
    union { float f; unsigned u; } v; v.f = f;
    unsigned r = v.u + 0x7fff + ((v.u >> 16) & 1);   // RNE
    return (unsigned short)(r >> 16);
}
__device__ inline float bf2f(unsigned short u) {
    union { unsigned u; float f; } v; v.u = ((unsigned)u) << 16; return v.f;
}

// ---------------------------------------------------------------------------
// fp32 -> bf16 contiguous convert (n4 = element count / 4)
// ---------------------------------------------------------------------------
__global__ __launch_bounds__(256) void convbf_kernel(
    const float* __restrict__ src, unsigned short* __restrict__ dst, int n4)
{
    for (int i = blockIdx.x * 256 + threadIdx.x; i < n4; i += gridDim.x * 256) {
        float4 v = ((const float4*)src)[i];
        u16x4 o; o.x = f2bf(v.x); o.y = f2bf(v.y); o.z = f2bf(v.z); o.w = f2bf(v.w);
        ((u16x4*)dst)[i] = o;
    }
}

// ---------------------------------------------------------------------------
// Ebf[t*B+b][h] = bf16(relu(emb[token(t,b)][h]))
// ---------------------------------------------------------------------------
__global__ __launch_bounds__(256) void embed_bf_kernel(
    const int* __restrict__ target, const float* __restrict__ emb,
    unsigned short* __restrict__ Ebf)
{
    int bid = blockIdx.x;                  // t*B+b
    int t = bid >> 5, b = bid & 31;
    int tok = (t == 0) ? 0 : target[b * T_ + (t - 1)];
    float4 v = ((const float4*)(emb + (size_t)tok * H_))[threadIdx.x];
    u16x4 o;
    o.x = f2bf(fmaxf(v.x, 0.f)); o.y = f2bf(fmaxf(v.y, 0.f));
    o.z = f2bf(fmaxf(v.z, 0.f)); o.w = f2bf(fmaxf(v.w, 0.f));
    ((u16x4*)(Ebf + (size_t)bid * H_))[threadIdx.x] = o;
}

// ---------------------------------------------------------------------------
// Attention collapse (step-invariant): scores = softmax_b(c_b), C = sum scores*enc_h
// ---------------------------------------------------------------------------
__global__ __launch_bounds__(256) void attn_pre_kernel(
    const float* __restrict__ enc_h, const float* __restrict__ l1_w,
    const float* __restrict__ l1_b, const float* __restrict__ l2_w,
    float* __restrict__ Cout, float* __restrict__ scores)
{
    __shared__ float L1h[96];
    __shared__ float sc[32];
    int tid = threadIdx.x, wv = tid >> 6, lane = tid & 63;
    for (int d = wv; d < 96; d += 4) {
        int b = d / 3, g = d - 3 * b;
        const float4* wp = (const float4*)(l1_w + (size_t)g * 2 * H_ + H_);
        const float4* ep = (const float4*)(enc_h + (size_t)b * H_);
        float s = 0.f;
        for (int q = lane; q < 256; q += 64) {
            float4 w4 = wp[q], e4 = ep[q];
            s += w4.x * e4.x + w4.y * e4.y + w4.z * e4.z + w4.w * e4.w;
        }
        for (int o = 32; o > 0; o >>= 1) s += __shfl_down(s, o);
        if (lane == 0) L1h[d] = s;
    }
    __syncthreads();
    if (tid < 32) {
        float cb = 0.f;
        for (int g = 0; g < 3; ++g) cb += l2_w[g] * (L1h[tid * 3 + g] + l1_b[g]);
        sc[tid] = cb;
    }
    __syncthreads();
    if (tid == 0) {
        float m = sc[0];
        for (int b = 1; b < 32; ++b) m = fmaxf(m, sc[b]);
        float s = 0.f;
        for (int b = 0; b < 32; ++b) { float e = expf(sc[b] - m); sc[b] = e; s += e; }
        float inv = 1.f / s;
        for (int b = 0; b < 32; ++b) { sc[b] *= inv; scores[b] = sc[b]; }
    }
    __syncthreads();
    float4 c = make_float4(0.f, 0.f, 0.f, 0.f);
    for (int b = 0; b < 32; ++b) {
        float4 e = ((const float4*)(enc_h + (size_t)b * H_))[tid];
        float ww = sc[b];
        c.x += ww * e.x; c.y += ww * e.y; c.z += ww * e.z; c.w += ww * e.w;
    }
    ((float4*)Cout)[tid] = c;
}

// ---------------------------------------------------------------------------
// wcC[n] = sum_k w_ih0[n][H+k] * C[k]
// ---------------------------------------------------------------------------
__global__ __launch_bounds__(256) void wcc_kernel(
    const float* __restrict__ w_ih0, const float* __restrict__ C,
    float* __restrict__ wcC)
{
    int row = blockIdx.x * 4 + (threadIdx.x >> 6);
    int lane = threadIdx.x & 63;
    const float4* wp = (const float4*)(w_ih0 + (size_t)row * 2 * H_ + H_);
    const float4* cp = (const float4*)C;
    float s = 0.f;
    for (int q = lane; q < 256; q += 64) {
        float4 w4 = wp[q], c4 = cp[q];
        s += w4.x * c4.x + w4.y * c4.y + w4.z * c4.z + w4.w * c4.w;
    }
    for (int o = 32; o > 0; o >>= 1) s += __shfl_down(s, o);
    if (lane == 0) wcC[row] = s;
}

// ---------------------------------------------------------------------------
// Big MFMA GEMM: out[row][col] = sum_k A[row][k]*Bb[col][k] + bias[row]
// ---------------------------------------------------------------------------
__global__ __launch_bounds__(256) void big_gemm_kernel(
    const void* __restrict__ Aptr, int lda, int abf,
    const unsigned short* __restrict__ Bb,
    const float* __restrict__ bias, int M, int outMode,
    void* __restrict__ outp)
{
    int tid = threadIdx.x, wv = tid >> 6, lane = tid & 63;
    int rlo = lane & 15, klane = (lane >> 4) * 8;
    int rowB = blockIdx.x * 128 + (wv >> 1) * 64;
    int colB = blockIdx.y * 128 + (wv & 1) * 64;
    const unsigned short* Ab = (const unsigned short*)Aptr;
    const float* Af = (const float*)Aptr;

    f32x4 acc[4][4];
    #pragma unroll
    for (int i = 0; i < 4; ++i)
        #pragma unroll
        for (int j = 0; j < 4; ++j) acc[i][j] = (f32x4){0.f, 0.f, 0.f, 0.f};

    for (int k0 = 0; k0 < H_; k0 += 32) {
        bf16x8 bfrag[4];
        #pragma unroll
        for (int ci = 0; ci < 4; ++ci) {
            int col = colB + ci * 16 + rlo;
            bfrag[ci] = *(const bf16x8*)(Bb + (size_t)col * H_ + k0 + klane);
        }
        #pragma unroll
        for (int ri = 0; ri < 4; ++ri) {
            int row = rowB + ri * 16 + rlo;
            bf16x8 af;
            if (abf) {
                af = *(const bf16x8*)(Ab + (size_t)row * lda + k0 + klane);
            } else {
                const float* ap = Af + (size_t)row * lda + k0 + klane;
                float4 x0 = *(const float4*)ap, x1 = *(const float4*)(ap + 4);
                af[0] = (short)f2bf(x0.x); af[1] = (short)f2bf(x0.y);
                af[2] = (short)f2bf(x0.z); af[3] = (short)f2bf(x0.w);
                af[4] = (short)f2bf(x1.x); af[5] = (short)f2bf(x1.y);
                af[6] = (short)f2bf(x1.z); af[7] = (short)f2bf(x1.w);
            }
            #pragma unroll
            for (int ci = 0; ci < 4; ++ci)
                acc[ri][ci] = __builtin_amdgcn_mfma_f32_16x16x32_bf16(
                    af, bfrag[ci], acc[ri][ci], 0, 0, 0);
        }
    }

    int rowoff = (lane >> 4) * 4;
    #pragma unroll
    for (int ri = 0; ri < 4; ++ri) {
        int row = rowB + ri * 16 + rowoff;
        float4 bs = *(const float4*)(bias + row);
        #pragma unroll
        for (int ci = 0; ci < 4; ++ci) {
            int col = colB + ci * 16 + rlo;
            float4 v;
            v.x = acc[ri][ci][0] + bs.x; v.y = acc[ri][ci][1] + bs.y;
            v.z = acc[ri][ci][2] + bs.z; v.w = acc[ri][ci][3] + bs.w;
            if (outMode == 1) {
                int tt = col >> 5, b = col & 31;
                *(float4*)((float*)outp + ((size_t)b * T_ + tt) * V_ + row) = v;
            } else {
                u16x4 o; o.x = f2bf(v.x); o.y = f2bf(v.y);
                o.z = f2bf(v.z); o.w = f2bf(v.w);
                *(u16x4*)((unsigned short*)outp + (size_t)col * M + row) = o;
            }
        }
    }
}

// ---------------------------------------------------------------------------
// Grid barrier (sense-reversal, device-scope). bar[0]=cnt, bar[1]=gen.
// ---------------------------------------------------------------------------
__device__ inline void grid_bar(unsigned* bar)
{
    __syncthreads();
    if (threadIdx.x == 0) {
        __threadfence();
        unsigned g = __hip_atomic_load(&bar[1], __ATOMIC_SEQ_CST, __HIP_MEMORY_SCOPE_AGENT);
        unsigned a = __hip_atomic_fetch_add(&bar[0], 1u, __ATOMIC_SEQ_CST, __HIP_MEMORY_SCOPE_AGENT);
        if (a == NBLK - 1u) {
            __hip_atomic_store(&bar[0], 0u, __ATOMIC_SEQ_CST, __HIP_MEMORY_SCOPE_AGENT);
            __hip_atomic_fetch_add(&bar[1], 1u, __ATOMIC_SEQ_CST, __HIP_MEMORY_SCOPE_AGENT);
        } else {
            while (__hip_atomic_load(&bar[1], __ATOMIC_SEQ_CST, __HIP_MEMORY_SCOPE_AGENT) == g)
                __builtin_amdgcn_s_sleep(2);
        }
        __threadfence();
    }
    __syncthreads();
}

// ---------------------------------------------------------------------------
// Persistent pipelined decode. Block -> (layer, feature slice).
//   layer 0: 32 blocks, 32 features each (gh via whh0; gi from G0)
//   layers 1-3: 64 blocks each, 16 features (gi + gh)
// Weights pinned in VGPRs: per block 96 rows x 1024 K bf16 = 96 VGPR/lane.
// Wave wv owns tasks q = 3*wv..3*wv+2, q = rg*4 + kc (rg = row-group of 16,
// kc = 256-wide K chunk). Per clock: MFMA into acc, LDS-reduce over kc,
// gate epilogue, write h (bf16) + Hist, grid barrier.
// ---------------------------------------------------------------------------
__global__ __launch_bounds__(512, 2) void decode_kernel(
    const unsigned short* __restrict__ whh0_bf,   // [3H][H]
    const unsigned short* __restrict__ wih_bf,    // [3][3H][H]
    const unsigned short* __restrict__ whh_bf,    // [3][3H][H]
    const unsigned short* __restrict__ G0,        // [TB][3H] bf16
    const float* __restrict__ b_ih0, const float* __restrict__ b_hh0,
    const float* __restrict__ b_ih,  const float* __restrict__ b_hh,
    const float* __restrict__ enc_hidden,         // [L][B][H] fp32
    unsigned short* __restrict__ hbf,             // [2][L][B][H] bf16
    unsigned short* __restrict__ Hist,            // [TB][H] bf16
    float* __restrict__ hid_out,                  // d_out + B*T*V
    unsigned* __restrict__ bar)
{
    __shared__ float sacc[6][4][16][33];          // rg, kc, row, col(+pad)
    const int tid = threadIdx.x;
    const int wv = tid >> 6, lane = tid & 63;
    const int rlo = lane & 15, klane = (lane >> 4) * 8;
    const int rowoff = (lane >> 4) * 4;
    const int bid = blockIdx.x;

    int layer, f0;
    if (bid < L0BLK) { layer = 0; f0 = bid << 5; }
    else { int r = bid - L0BLK; layer = 1 + (r >> 6); f0 = (r & 63) << 4; }

    const unsigned short* Wih_l = (layer >= 1) ? wih_bf + (size_t)(layer - 1) * N3H * H_ : nullptr;
    const unsigned short* Whh_l = (layer >= 1) ? whh_bf + (size_t)(layer - 1) * N3H * H_ : whh0_bf;

    // ---- weight preload into registers ----
    bf16x8 wreg[3][8];
    int rgv[3], kcv[3];
    #pragma unroll
    for (int i = 0; i < 3; ++i) {
        int q = wv * 3 + i;                 // 0..23
        int rg = q >> 2, kc = q & 3;
        rgv[i] = rg; kcv[i] = kc;
        int wrow; const unsigned short* Wm;
        if (layer == 0)      { wrow = (rg >> 1) * H_ + f0 + (rg & 1) * 16; Wm = Whh_l; }
        else if (rg < 3)     { wrow = rg * H_ + f0;        Wm = Wih_l; }
        else                 { wrow = (rg - 3) * H_ + f0;  Wm = Whh_l; }
        const unsigned short* p = Wm + (size_t)(wrow + rlo) * H_ + kc * 256 + klane;
        #pragma unroll
        for (int s = 0; s < 8; ++s) wreg[i][s] = *(const bf16x8*)(p + s * 32);
    }

    // ---- bias + hold-state registers (epilogue role fixed per thread) ----
    const float* bihp = (layer == 0) ? b_ih0 : b_ih + (size_t)(layer - 1) * N3H;
    const float* bhhp = (layer == 0) ? b_hh0 : b_hh + (size_t)(layer - 1) * N3H;
    int jj, eb0;
    float hold0, hold1 = 0.f;
    if (layer == 0) {
        jj = f0 + (tid & 31);
        eb0 = tid >> 5;                     // batch for rep0; rep1 = eb0+16
        hold0 = enc_hidden[(size_t)eb0 * H_ + jj];
        hold1 = enc_hidden[(size_t)(eb0 + 16) * H_ + jj];
    } else {
        jj = f0 + (tid >> 5);
        eb0 = tid & 31;
        hold0 = enc_hidden[(size_t)layer * B_ * H_ + (size_t)eb0 * H_ + jj];
    }
    const float bir = bihp[jj], biz = bihp[H_ + jj], bin_ = bihp[2 * H_ + jj];
    const float bhr = bhhp[jj], bhz = bhhp[H_ + jj], bhn = bhhp[2 * H_ + jj];

    const size_t BH = (size_t)B_ * H_;

    for (int c = 0; c < T_ + L_ - 1; ++c) {
        int t = c - layer;
        if (t >= 0 && t < T_) {
            int pw = t & 1, pr = pw ^ 1;
            const unsigned short* hown  = hbf + ((size_t)pr * L_ + layer) * BH;
            const unsigned short* hprev = (layer > 0)
                ? hbf + ((size_t)pw * L_ + (layer - 1)) * BH : nullptr;

            f32x4 acc[3][2];
            #pragma unroll
            for (int i = 0; i < 3; ++i) {
                acc[i][0] = (f32x4){0.f, 0.f, 0.f, 0.f};
                acc[i][1] = (f32x4){0.f, 0.f, 0.f, 0.f};
            }

            #pragma unroll
            for (int i = 0; i < 3; ++i) {
                const unsigned short* hsrc = (layer == 0 || rgv[i] >= 3) ? hown : hprev;
                const unsigned short* hp = hsrc + (size_t)rlo * H_ + kcv[i] * 256 + klane;
                #pragma unroll
                for (int s = 0; s < 8; ++s) {
                    bf16x8 b0 = *(const bf16x8*)(hp + s * 32);
                    bf16x8 b1 = *(const bf16x8*)(hp + 16 * H_ + s * 32);
                    acc[i][0] = __builtin_amdgcn_mfma_f32_16x16x32_bf16(wreg[i][s], b0, acc[i][0], 0, 0, 0);
                    acc[i][1] = __builtin_amdgcn_mfma_f32_16x16x32_bf16(wreg[i][s], b1, acc[i][1], 0, 0, 0);
                }
            }

            #pragma unroll
            for (int i = 0; i < 3; ++i)
                #pragma unroll
                for (int r = 0; r < 4; ++r) {
                    sacc[rgv[i]][kcv[i]][rowoff + r][rlo]      = acc[i][0][r];
                    sacc[rgv[i]][kcv[i]][rowoff + r][16 + rlo] = acc[i][1][r];
                }
            __syncthreads();

            if (layer > 0) {
                int f = tid >> 5, b = tid & 31;
                float ir = bir, iz = biz, in_ = bin_;
                float hr = bhr, hz = bhz, hn = bhn;
                #pragma unroll
                for (int kc = 0; kc < 4; ++kc) {
                    ir += sacc[0][kc][f][b]; iz += sacc[1][kc][f][b]; in_ += sacc[2][kc][f][b];
                    hr += sacc[3][kc][f][b]; hz += sacc[4][kc][f][b]; hn += sacc[5][kc][f][b];
                }
                float r = 1.f / (1.f + expf(-(ir + hr)));
                float z = 1.f / (1.f + expf(-(iz + hz)));
                float n = tanhf(in_ + r * hn);
                float hnew = (1.f - z) * n + z * hold0;
                hold0 = hnew;
                unsigned short hb16 = f2bf(hnew);
                hbf[((size_t)pw * L_ + layer) * BH + (size_t)b * H_ + jj] = hb16;
                if (layer == L_ - 1) Hist[((size_t)t * B_ + b) * H_ + jj] = hb16;
                if (t == T_ - 1) hid_out[(size_t)layer * BH + (size_t)b * H_ + jj] = hnew;
            } else {
                int fi = tid & 31;
                int rghalf = fi >> 4, fr = fi & 15;
                // rep 0 (batch eb0)
                {
                    int b = eb0;
                    const unsigned short* g0p = G0 + ((size_t)t * B_ + b) * N3H;
                    float ir = bf2f(g0p[jj]) + bir;
                    float iz = bf2f(g0p[H_ + jj]) + biz;
                    float in_ = bf2f(g0p[2 * H_ + jj]) + bin_;
                    float hr = bhr, hz = bhz, hn = bhn;
                    #pragma unroll
                    for (int kc = 0; kc < 4; ++kc) {
                        hr += sacc[rghalf][kc][fr][b];
                        hz += sacc[2 + rghalf][kc][fr][b];
                        hn += sacc[4 + rghalf][kc][fr][b];
                    }
                    float r = 1.f / (1.f + expf(-(ir + hr)));
                    float z = 1.f / (1.f + expf(-(iz + hz)));
                    float n = tanhf(in_ + r * hn);
                    float hnew = (1.f - z) * n + z * hold0;
                    hold0 = hnew;
                    hbf[((size_t)pw * L_) * BH + (size_t)b * H_ + jj] = f2bf(hnew);
                    if (t == T_ - 1) hid_out[(size_t)b * H_ + jj] = hnew;
                }
                // rep 1 (batch eb0+16)
                {
                    int b = eb0 + 16;
                    const unsigned short* g0p = G0 + ((size_t)t * B_ + b) * N3H;
                    float ir = bf2f(g0p[jj]) + bir;
                    float iz = bf2f(g0p[H_ + jj]) + biz;
                    float in_ = bf2f(g0p[2 * H_ + jj]) + bin_;
                    float hr = bhr, hz = bhz, hn = bhn;
                    #pragma unroll
                    for (int kc = 0; kc < 4; ++kc) {
                        hr += sacc[rghalf][kc][fr][b];
                        hz += sacc[2 + rghalf][kc][fr][b];
                        hn += sacc[4 + rghalf][kc][fr][b];
                    }
                    float r = 1.f / (1.f + expf(-(ir + hr)));
                    float z = 1.f / (1.f + expf(-(iz + hz)));
                    float n = tanhf(in_ + r * hn);
                    float hnew = (1.f - z) * n + z * hold1;
                    hold1 = hnew;
                    hbf[((size_t)pw * L_) * BH + (size_t)b * H_ + jj] = f2bf(hnew);
                    if (t == T_ - 1) hid_out[(size_t)b * H_ + jj] = hnew;
                }
            }
        }
        grid_bar(bar);
    }
}

// ---------------------------------------------------------------------------
// In-place log_softmax over rows of V_ (float4 vectorized)
// ---------------------------------------------------------------------------
__global__ __launch_bounds__(256) void logsoftmax_kernel(float* __restrict__ dout)
{
    __shared__ float red[256];
    float4* x4 = (float4*)(dout + (size_t)blockIdx.x * V_);
    const int N4 = V_ / 4;
    int tid = threadIdx.x;

    float m = -INFINITY;
    for (int i = tid; i < N4; i += 256) {
        float4 v = x4[i];
        m = fmaxf(m, fmaxf(fmaxf(v.x, v.y), fmaxf(v.z, v.w)));
    }
    red[tid] = m; __syncthreads();
    for (int s = 128; s > 0; s >>= 1) {
        if (tid < s) red[tid] = fmaxf(red[tid], red[tid + s]);
        __syncthreads();
    }
    m = red[0]; __syncthreads();

    float s = 0.f;
    for (int i = tid; i < N4; i += 256) {
        float4 v = x4[i];
        s += expf(v.x - m) + expf(v.y - m) + expf(v.z - m) + expf(v.w - m);
    }
    red[tid] = s; __syncthreads();
    for (int ss = 128; ss > 0; ss >>= 1) {
        if (tid < ss) red[tid] += red[tid + ss];
        __syncthreads();
    }
    float lse = m + logf(red[0]);
    __syncthreads();

    for (int i = tid; i < N4; i += 256) {
        float4 v = x4[i];
        v.x -= lse; v.y -= lse; v.z -= lse; v.w -= lse;
        x4[i] = v;
    }
}

// ---------------------------------------------------------------------------
extern "C" void kernel_launch(void* const* d_in, const int* in_sizes, int n_in,
                              void* d_out, int out_size, void* d_ws, size_t ws_size,
                              hipStream_t stream)
{
    (void)in_sizes; (void)n_in; (void)out_size;

    const float* enc_hidden = (const float*)d_in[1];   // [L][B][H]; layer0 = enc_h
    const int*   target     = (const int*)  d_in[2];
    const float* emb        = (const float*)d_in[3];
    const float* w_ih0      = (const float*)d_in[4];   // [3H][2H]
    const float* w_hh0      = (const float*)d_in[5];   // [3H][H]
    const float* b_ih0      = (const float*)d_in[6];
    const float* b_hh0      = (const float*)d_in[7];
    const float* w_ih       = (const float*)d_in[8];   // [3][3H][H]
    const float* w_hh       = (const float*)d_in[9];
    const float* b_ih       = (const float*)d_in[10];
    const float* b_hh       = (const float*)d_in[11];
    const float* out_w      = (const float*)d_in[12];  // [V][H]
    const float* out_b      = (const float*)d_in[13];
    const float* l1_w       = (const float*)d_in[14];
    const float* l1_b       = (const float*)d_in[15];
    const float* l2_w       = (const float*)d_in[16];
    float* out = (float*)d_out;

    // --- workspace carve ---
    char* w = (char*)d_ws;
    auto alloc = [&](size_t bytes) -> char* {
        char* p = w; w += (bytes + 255) & ~(size_t)255; return p;
    };
    unsigned short* whh0_bf = (unsigned short*)alloc((size_t)N3H * H_ * 2);
    unsigned short* wih_bf  = (unsigned short*)alloc((size_t)3 * N3H * H_ * 2);
    unsigned short* whh_bf  = (unsigned short*)alloc((size_t)3 * N3H * H_ * 2);
    unsigned short* Ebf     = (unsigned short*)alloc((size_t)TB_ * H_ * 2);
    unsigned short* G0      = (unsigned short*)alloc((size_t)TB_ * N3H * 2);
    unsigned short* Hist    = (unsigned short*)alloc((size_t)TB_ * H_ * 2);
    unsigned short* hbf     = (unsigned short*)alloc((size_t)2 * L_ * B_ * H_ * 2);
    float*          Cbuf    = (float*)alloc(H_ * 4);
    float*          scores  = (float*)alloc(256);
    float*          wcC     = (float*)alloc(N3H * 4);
    unsigned*       bar     = (unsigned*)alloc(256);
    size_t used = (size_t)(w - (char*)d_ws);
    unsigned short* outw_bf = nullptr;
    if (used + (size_t)V_ * H_ * 2 + 256 <= ws_size)
        outw_bf = (unsigned short*)alloc((size_t)V_ * H_ * 2);

    const size_t LBH = (size_t)L_ * B_ * H_;

    hipMemsetAsync(bar, 0, 8, stream);

    // --- one-time precompute ---
    convbf_kernel<<<512, 256, 0, stream>>>(w_hh0, whh0_bf, N3H * H_ / 4);
    convbf_kernel<<<1024, 256, 0, stream>>>(w_ih, wih_bf, 3 * N3H * H_ / 4);
    convbf_kernel<<<1024, 256, 0, stream>>>(w_hh, whh_bf, 3 * N3H * H_ / 4);
    if (outw_bf)
        convbf_kernel<<<2048, 256, 0, stream>>>(out_w, outw_bf, V_ * H_ / 4);
    embed_bf_kernel<<<TB_, 256, 0, stream>>>(target, emb, Ebf);
    convbf_kernel<<<128, 256, 0, stream>>>(enc_hidden, hbf + LBH, (int)(LBH / 4));
    attn_pre_kernel<<<1, 256, 0, stream>>>(enc_hidden, l1_w, l1_b, l2_w, Cbuf, scores);
    wcc_kernel<<<N3H / 4, 256, 0, stream>>>(w_ih0, Cbuf, wcC);
    big_gemm_kernel<<<dim3(N3H / 128, TB_ / 128), 256, 0, stream>>>(
        w_ih0, 2 * H_, 0, Ebf, wcC, N3H, 0, G0);

    // --- persistent pipelined decode (one launch, 103 grid barriers) ---
    decode_kernel<<<NBLK, 512, 0, stream>>>(
        whh0_bf, wih_bf, whh_bf, G0, b_ih0, b_hh0, b_ih, b_hh,
        enc_hidden, hbf, Hist, out + (size_t)B_ * T_ * V_, bar);

    // --- deferred logits GEMM + log_softmax ---
    if (outw_bf)
        big_gemm_kernel<<<dim3(V_ / 128, TB_ / 128), 256, 0, stream>>>(
            outw_bf, H_, 1, Hist, out_b, V_, 1, out);
    else
        big_gemm_kernel<<<dim3(V_ / 128, TB_ / 128), 256, 0, stream>>>(
            out_w, H_, 0, Hist, out_b, V_, 1, out);
    logsoftmax_kernel<<<TB_, 256, 0, stream>>>(out);

    hipMemcpyAsync(out + (size_t)B_ * T_ * V_ + LBH, scores, B_ * 4,
                   hipMemcpyDeviceToDevice, stream);
}

// Round 4
// 5849.162 us; speedup vs baseline: 3.4573x; 1.1452x over previous
//
#include <hip/hip_runtime.h>
#include <hip/hip_bf16.h>
#include <math.h>

#define B_ 32
#define H_ 1024
#define V_ 32000
#define T_ 100
#define L_ 4
#define TB_ (T_*B_)      // 3200
#define N3H (3*H_)       // 3072
#define NBLK 224         // decode grid: 32 (layer0) + 3*64 (layers 1-3)
#define L0BLK 32
#define FSTRIDE 16       // flag padding: 16 uints = 64B per block

typedef __attribute__((ext_vector_type(8))) short bf16x8;
typedef __attribute__((ext_vector_type(4))) float f32x4;
typedef __attribute__((ext_vector_type(4))) unsigned short u16x4;

__device__ inline unsigned short f2bf(float f) {
    union { float f; unsigned u; } v; v.f = f;
    unsigned r = v.u + 0x7fff + ((v.u >> 16) & 1);   // RNE
    return (unsigned short)(r >> 16);
}
__device__ inline float bf2f(unsigned short u) {
    union { unsigned u; float f; } v; v.u = ((unsigned)u) << 16; return v.f;
}

// ---------------------------------------------------------------------------
// fp32 -> bf16 contiguous convert (n4 = element count / 4)
// ---------------------------------------------------------------------------
__global__ __launch_bounds__(256) void convbf_kernel(
    const float* __restrict__ src, unsigned short* __restrict__ dst, int n4)
{
    for (int i = blockIdx.x * 256 + threadIdx.x; i < n4; i += gridDim.x * 256) {
        float4 v = ((const float4*)src)[i];
        u16x4 o; o.x = f2bf(v.x); o.y = f2bf(v.y); o.z = f2bf(v.z); o.w = f2bf(v.w);
        ((u16x4*)dst)[i] = o;
    }
}

// ---------------------------------------------------------------------------
// Ebf[t*B+b][h] = bf16(relu(emb[token(t,b)][h]))
// ---------------------------------------------------------------------------
__global__ __launch_bounds__(256) void embed_bf_kernel(
    const int* __restrict__ target, const float* __restrict__ emb,
    unsigned short* __restrict__ Ebf)
{
    int bid = blockIdx.x;                  // t*B+b
    int t = bid >> 5, b = bid & 31;
    int tok = (t == 0) ? 0 : target[b * T_ + (t - 1)];
    float4 v = ((const float4*)(emb + (size_t)tok * H_))[threadIdx.x];
    u16x4 o;
    o.x = f2bf(fmaxf(v.x, 0.f)); o.y = f2bf(fmaxf(v.y, 0.f));
    o.z = f2bf(fmaxf(v.z, 0.f)); o.w = f2bf(fmaxf(v.w, 0.f));
    ((u16x4*)(Ebf + (size_t)bid * H_))[threadIdx.x] = o;
}

// ---------------------------------------------------------------------------
// Attention collapse (step-invariant): scores = softmax_b(c_b), C = sum scores*enc_h
// ---------------------------------------------------------------------------
__global__ __launch_bounds__(256) void attn_pre_kernel(
    const float* __restrict__ enc_h, const float* __restrict__ l1_w,
    const float* __restrict__ l1_b, const float* __restrict__ l2_w,
    float* __restrict__ Cout, float* __restrict__ scores)
{
    __shared__ float L1h[96];
    __shared__ float sc[32];
    int tid = threadIdx.x, wv = tid >> 6, lane = tid & 63;
    for (int d = wv; d < 96; d += 4) {
        int b = d / 3, g = d - 3 * b;
        const float4* wp = (const float4*)(l1_w + (size_t)g * 2 * H_ + H_);
        const float4* ep = (const float4*)(enc_h + (size_t)b * H_);
        float s = 0.f;
        for (int q = lane; q < 256; q += 64) {
            float4 w4 = wp[q], e4 = ep[q];
            s += w4.x * e4.x + w4.y * e4.y + w4.z * e4.z + w4.w * e4.w;
        }
        for (int o = 32; o > 0; o >>= 1) s += __shfl_down(s, o);
        if (lane == 0) L1h[d] = s;
    }
    __syncthreads();
    if (tid < 32) {
        float cb = 0.f;
        for (int g = 0; g < 3; ++g) cb += l2_w[g] * (L1h[tid * 3 + g] + l1_b[g]);
        sc[tid] = cb;
    }
    __syncthreads();
    if (tid == 0) {
        float m = sc[0];
        for (int b = 1; b < 32; ++b) m = fmaxf(m, sc[b]);
        float s = 0.f;
        for (int b = 0; b < 32; ++b) { float e = expf(sc[b] - m); sc[b] = e; s += e; }
        float inv = 1.f / s;
        for (int b = 0; b < 32; ++b) { sc[b] *= inv; scores[b] = sc[b]; }
    }
    __syncthreads();
    float4 c = make_float4(0.f, 0.f, 0.f, 0.f);
    for (int b = 0; b < 32; ++b) {
        float4 e = ((const float4*)(enc_h + (size_t)b * H_))[tid];
        float ww = sc[b];
        c.x += ww * e.x; c.y += ww * e.y; c.z += ww * e.z; c.w += ww * e.w;
    }
    ((float4*)Cout)[tid] = c;
}

// ---------------------------------------------------------------------------
// wcC[n] = sum_k w_ih0[n][H+k] * C[k]
// ---------------------------------------------------------------------------
__global__ __launch_bounds__(256) void wcc_kernel(
    const float* __restrict__ w_ih0, const float* __restrict__ C,
    float* __restrict__ wcC)
{
    int row = blockIdx.x * 4 + (threadIdx.x >> 6);
    int lane = threadIdx.x & 63;
    const float4* wp = (const float4*)(w_ih0 + (size_t)row * 2 * H_ + H_);
    const float4* cp = (const float4*)C;
    float s = 0.f;
    for (int q = lane; q < 256; q += 64) {
        float4 w4 = wp[q], c4 = cp[q];
        s += w4.x * c4.x + w4.y * c4.y + w4.z * c4.z + w4.w * c4.w;
    }
    for (int o = 32; o > 0; o >>= 1) s += __shfl_down(s, o);
    if (lane == 0) wcC[row] = s;
}

// ---------------------------------------------------------------------------
// Big MFMA GEMM: out[row][col] = sum_k A[row][k]*Bb[col][k] + bias[row]
// ---------------------------------------------------------------------------
__global__ __launch_bounds__(256) void big_gemm_kernel(
    const void* __restrict__ Aptr, int lda, int abf,
    const unsigned short* __restrict__ Bb,
    const float* __restrict__ bias, int M, int outMode,
    void* __restrict__ outp)
{
    int tid = threadIdx.x, wv = tid >> 6, lane = tid & 63;
    int rlo = lane & 15, klane = (lane >> 4) * 8;
    int rowB = blockIdx.x * 128 + (wv >> 1) * 64;
    int colB = blockIdx.y * 128 + (wv & 1) * 64;
    const unsigned short* Ab = (const unsigned short*)Aptr;
    const float* Af = (const float*)Aptr;

    f32x4 acc[4][4];
    #pragma unroll
    for (int i = 0; i < 4; ++i)
        #pragma unroll
        for (int j = 0; j < 4; ++j) acc[i][j] = (f32x4){0.f, 0.f, 0.f, 0.f};

    for (int k0 = 0; k0 < H_; k0 += 32) {
        bf16x8 bfrag[4];
        #pragma unroll
        for (int ci = 0; ci < 4; ++ci) {
            int col = colB + ci * 16 + rlo;
            bfrag[ci] = *(const bf16x8*)(Bb + (size_t)col * H_ + k0 + klane);
        }
        #pragma unroll
        for (int ri = 0; ri < 4; ++ri) {
            int row = rowB + ri * 16 + rlo;
            bf16x8 af;
            if (abf) {
                af = *(const bf16x8*)(Ab + (size_t)row * lda + k0 + klane);
            } else {
                const float* ap = Af + (size_t)row * lda + k0 + klane;
                float4 x0 = *(const float4*)ap, x1 = *(const float4*)(ap + 4);
                af[0] = (short)f2bf(x0.x); af[1] = (short)f2bf(x0.y);
                af[2] = (short)f2bf(x0.z); af[3] = (short)f2bf(x0.w);
                af[4] = (short)f2bf(x1.x); af[5] = (short)f2bf(x1.y);
                af[6] = (short)f2bf(x1.z); af[7] = (short)f2bf(x1.w);
            }
            #pragma unroll
            for (int ci = 0; ci < 4; ++ci)
                acc[ri][ci] = __builtin_amdgcn_mfma_f32_16x16x32_bf16(
                    af, bfrag[ci], acc[ri][ci], 0, 0, 0);
        }
    }

    int rowoff = (lane >> 4) * 4;
    #pragma unroll
    for (int ri = 0; ri < 4; ++ri) {
        int row = rowB + ri * 16 + rowoff;
        float4 bs = *(const float4*)(bias + row);
        #pragma unroll
        for (int ci = 0; ci < 4; ++ci) {
            int col = colB + ci * 16 + rlo;
            float4 v;
            v.x = acc[ri][ci][0] + bs.x; v.y = acc[ri][ci][1] + bs.y;
            v.z = acc[ri][ci][2] + bs.z; v.w = acc[ri][ci][3] + bs.w;
            if (outMode == 1) {
                int tt = col >> 5, b = col & 31;
                *(float4*)((float*)outp + ((size_t)b * T_ + tt) * V_ + row) = v;
            } else {
                u16x4 o; o.x = f2bf(v.x); o.y = f2bf(v.y);
                o.z = f2bf(v.z); o.w = f2bf(v.w);
                *(u16x4*)((unsigned short*)outp + (size_t)col * M + row) = o;
            }
        }
    }
}

// ---------------------------------------------------------------------------
// Combiner grid barrier: parallel per-block flag stores (64B-padded),
// block 0 aggregates via __syncthreads_and over 224 watcher threads,
// publishes `done`; everyone polls the single read-shared done line.
// ---------------------------------------------------------------------------
__device__ inline void grid_bar2(unsigned* flags, unsigned* done, unsigned round)
{
    __syncthreads();
    if (threadIdx.x == 0) {
        __threadfence();
        __hip_atomic_store(&flags[(size_t)blockIdx.x * FSTRIDE], round,
                           __ATOMIC_RELEASE, __HIP_MEMORY_SCOPE_AGENT);
    }
    if (blockIdx.x == 0) {
        int ok = (threadIdx.x >= NBLK) ? 1 : 0;
        do {
            if (!ok)
                ok = (__hip_atomic_load(&flags[(size_t)threadIdx.x * FSTRIDE],
                                        __ATOMIC_ACQUIRE, __HIP_MEMORY_SCOPE_AGENT) >= round);
        } while (!__syncthreads_and(ok));
        if (threadIdx.x == 0)
            __hip_atomic_store(done, round, __ATOMIC_RELEASE, __HIP_MEMORY_SCOPE_AGENT);
    }
    if (threadIdx.x == 0) {
        while (__hip_atomic_load(done, __ATOMIC_ACQUIRE, __HIP_MEMORY_SCOPE_AGENT) < round)
            __builtin_amdgcn_s_sleep(1);
        __threadfence();
    }
    __syncthreads();
}

// ---------------------------------------------------------------------------
// Persistent pipelined decode. Block -> (layer, feature slice).
//   layer 0: 32 blocks, 32 features each (gh via whh0; gi from G0)
//   layers 1-3: 64 blocks each, 16 features (gi + gh)
// Weights pinned in registers (96 regs/lane). Per clock: MFMA into acc,
// LDS-reduce over kc, gate epilogue, write h (bf16) + Hist, grid barrier.
// ---------------------------------------------------------------------------
__global__ __launch_bounds__(512, 2) void decode_kernel(
    const unsigned short* __restrict__ whh0_bf,   // [3H][H]
    const unsigned short* __restrict__ wih_bf,    // [3][3H][H]
    const unsigned short* __restrict__ whh_bf,    // [3][3H][H]
    const unsigned short* __restrict__ G0,        // [TB][3H] bf16
    const float* __restrict__ b_ih0, const float* __restrict__ b_hh0,
    const float* __restrict__ b_ih,  const float* __restrict__ b_hh,
    const float* __restrict__ enc_hidden,         // [L][B][H] fp32
    unsigned short* __restrict__ hbf,             // [2][L][B][H] bf16
    unsigned short* __restrict__ Hist,            // [TB][H] bf16
    float* __restrict__ hid_out,                  // d_out + B*T*V
    unsigned* __restrict__ flags, unsigned* __restrict__ done)
{
    __shared__ float sacc[6][4][16][34];          // rg, kc, row, col (+2 pad: 2-way free)
    const int tid = threadIdx.x;
    const int wv = tid >> 6, lane = tid & 63;
    const int rlo = lane & 15, klane = (lane >> 4) * 8;
    const int rowoff = (lane >> 4) * 4;
    const int bid = blockIdx.x;

    int layer, f0;
    if (bid < L0BLK) { layer = 0; f0 = bid << 5; }
    else { int r = bid - L0BLK; layer = 1 + (r >> 6); f0 = (r & 63) << 4; }

    const unsigned short* Wih_l = (layer >= 1) ? wih_bf + (size_t)(layer - 1) * N3H * H_ : nullptr;
    const unsigned short* Whh_l = (layer >= 1) ? whh_bf + (size_t)(layer - 1) * N3H * H_ : whh0_bf;

    // ---- weight preload into registers ----
    bf16x8 wreg[3][8];
    int rgv[3], kcv[3];
    #pragma unroll
    for (int i = 0; i < 3; ++i) {
        int q = wv * 3 + i;                 // 0..23
        int rg = q >> 2, kc = q & 3;
        rgv[i] = rg; kcv[i] = kc;
        int wrow; const unsigned short* Wm;
        if (layer == 0)      { wrow = (rg >> 1) * H_ + f0 + (rg & 1) * 16; Wm = Whh_l; }
        else if (rg < 3)     { wrow = rg * H_ + f0;        Wm = Wih_l; }
        else                 { wrow = (rg - 3) * H_ + f0;  Wm = Whh_l; }
        const unsigned short* p = Wm + (size_t)(wrow + rlo) * H_ + kc * 256 + klane;
        #pragma unroll
        for (int s = 0; s < 8; ++s) wreg[i][s] = *(const bf16x8*)(p + s * 32);
    }

    // ---- bias + hold-state registers ----
    const float* bihp = (layer == 0) ? b_ih0 : b_ih + (size_t)(layer - 1) * N3H;
    const float* bhhp = (layer == 0) ? b_hh0 : b_hh + (size_t)(layer - 1) * N3H;
    int jj, eb0;
    float hold0, hold1 = 0.f;
    if (layer == 0) {
        jj = f0 + (tid & 31);
        eb0 = tid >> 5;                     // batch for rep0; rep1 = eb0+16
        hold0 = enc_hidden[(size_t)eb0 * H_ + jj];
        hold1 = enc_hidden[(size_t)(eb0 + 16) * H_ + jj];
    } else {
        jj = f0 + (tid >> 5);
        eb0 = tid & 31;
        hold0 = enc_hidden[(size_t)layer * B_ * H_ + (size_t)eb0 * H_ + jj];
    }
    const float bir = bihp[jj], biz = bihp[H_ + jj], bin_ = bihp[2 * H_ + jj];
    const float bhr = bhhp[jj], bhz = bhhp[H_ + jj], bhn = bhhp[2 * H_ + jj];

    const size_t BH = (size_t)B_ * H_;

    for (int c = 0; c < T_ + L_ - 1; ++c) {
        int t = c - layer;
        if (t >= 0 && t < T_) {
            int pw = t & 1, pr = pw ^ 1;
            const unsigned short* hown  = hbf + ((size_t)pr * L_ + layer) * BH;
            const unsigned short* hprev = (layer > 0)
                ? hbf + ((size_t)pw * L_ + (layer - 1)) * BH : nullptr;

            f32x4 acc[3][2];
            #pragma unroll
            for (int i = 0; i < 3; ++i) {
                acc[i][0] = (f32x4){0.f, 0.f, 0.f, 0.f};
                acc[i][1] = (f32x4){0.f, 0.f, 0.f, 0.f};
            }

            #pragma unroll
            for (int i = 0; i < 3; ++i) {
                const unsigned short* hsrc = (layer == 0 || rgv[i] >= 3) ? hown : hprev;
                const unsigned short* hp = hsrc + (size_t)rlo * H_ + kcv[i] * 256 + klane;
                #pragma unroll
                for (int s = 0; s < 8; ++s) {
                    bf16x8 b0 = *(const bf16x8*)(hp + s * 32);
                    bf16x8 b1 = *(const bf16x8*)(hp + 16 * H_ + s * 32);
                    acc[i][0] = __builtin_amdgcn_mfma_f32_16x16x32_bf16(wreg[i][s], b0, acc[i][0], 0, 0, 0);
                    acc[i][1] = __builtin_amdgcn_mfma_f32_16x16x32_bf16(wreg[i][s], b1, acc[i][1], 0, 0, 0);
                }
            }

            #pragma unroll
            for (int i = 0; i < 3; ++i)
                #pragma unroll
                for (int r = 0; r < 4; ++r) {
                    sacc[rgv[i]][kcv[i]][rowoff + r][rlo]      = acc[i][0][r];
                    sacc[rgv[i]][kcv[i]][rowoff + r][16 + rlo] = acc[i][1][r];
                }
            __syncthreads();

            if (layer > 0) {
                int f = tid >> 5, b = tid & 31;
                float ir = bir, iz = biz, in_ = bin_;
                float hr = bhr, hz = bhz, hn = bhn;
                #pragma unroll
                for (int kc = 0; kc < 4; ++kc) {
                    ir += sacc[0][kc][f][b]; iz += sacc[1][kc][f][b]; in_ += sacc[2][kc][f][b];
                    hr += sacc[3][kc][f][b]; hz += sacc[4][kc][f][b]; hn += sacc[5][kc][f][b];
                }
                float r = 1.f / (1.f + expf(-(ir + hr)));
                float z = 1.f / (1.f + expf(-(iz + hz)));
                float n = tanhf(in_ + r * hn);
                float hnew = (1.f - z) * n + z * hold0;
                hold0 = hnew;
                unsigned short hb16 = f2bf(hnew);
                hbf[((size_t)pw * L_ + layer) * BH + (size_t)b * H_ + jj] = hb16;
                if (layer == L_ - 1) Hist[((size_t)t * B_ + b) * H_ + jj] = hb16;
                if (t == T_ - 1) hid_out[(size_t)layer * BH + (size_t)b * H_ + jj] = hnew;
            } else {
                int fi = tid & 31;
                int rghalf = fi >> 4, fr = fi & 15;
                {
                    int b = eb0;
                    const unsigned short* g0p = G0 + ((size_t)t * B_ + b) * N3H;
                    float ir = bf2f(g0p[jj]) + bir;
                    float iz = bf2f(g0p[H_ + jj]) + biz;
                    float in_ = bf2f(g0p[2 * H_ + jj]) + bin_;
                    float hr = bhr, hz = bhz, hn = bhn;
                    #pragma unroll
                    for (int kc = 0; kc < 4; ++kc) {
                        hr += sacc[rghalf][kc][fr][b];
                        hz += sacc[2 + rghalf][kc][fr][b];
                        hn += sacc[4 + rghalf][kc][fr][b];
                    }
                    float r = 1.f / (1.f + expf(-(ir + hr)));
                    float z = 1.f / (1.f + expf(-(iz + hz)));
                    float n = tanhf(in_ + r * hn);
                    float hnew = (1.f - z) * n + z * hold0;
                    hold0 = hnew;
                    hbf[((size_t)pw * L_) * BH + (size_t)b * H_ + jj] = f2bf(hnew);
                    if (t == T_ - 1) hid_out[(size_t)b * H_ + jj] = hnew;
                }
                {
                    int b = eb0 + 16;
                    const unsigned short* g0p = G0 + ((size_t)t * B_ + b) * N3H;
                    float ir = bf2f(g0p[jj]) + bir;
                    float iz = bf2f(g0p[H_ + jj]) + biz;
                    float in_ = bf2f(g0p[2 * H_ + jj]) + bin_;
                    float hr = bhr, hz = bhz, hn = bhn;
                    #pragma unroll
                    for (int kc = 0; kc < 4; ++kc) {
                        hr += sacc[rghalf][kc][fr][b];
                        hz += sacc[2 + rghalf][kc][fr][b];
                        hn += sacc[4 + rghalf][kc][fr][b];
                    }
                    float r = 1.f / (1.f + expf(-(ir + hr)));
                    float z = 1.f / (1.f + expf(-(iz + hz)));
                    float n = tanhf(in_ + r * hn);
                    float hnew = (1.f - z) * n + z * hold1;
                    hold1 = hnew;
                    hbf[((size_t)pw * L_) * BH + (size_t)b * H_ + jj] = f2bf(hnew);
                    if (t == T_ - 1) hid_out[(size_t)b * H_ + jj] = hnew;
                }
            }
        }
        grid_bar2(flags, done, (unsigned)(c + 1));
    }
}

// ---------------------------------------------------------------------------
// In-place log_softmax over rows of V_ (float4 vectorized)
// ---------------------------------------------------------------------------
__global__ __launch_bounds__(256) void logsoftmax_kernel(float* __restrict__ dout)
{
    __shared__ float red[256];
    float4* x4 = (float4*)(dout + (size_t)blockIdx.x * V_);
    const int N4 = V_ / 4;
    int tid = threadIdx.x;

    float m = -INFINITY;
    for (int i = tid; i < N4; i += 256) {
        float4 v = x4[i];
        m = fmaxf(m, fmaxf(fmaxf(v.x, v.y), fmaxf(v.z, v.w)));
    }
    red[tid] = m; __syncthreads();
    for (int s = 128; s > 0; s >>= 1) {
        if (tid < s) red[tid] = fmaxf(red[tid], red[tid + s]);
        __syncthreads();
    }
    m = red[0]; __syncthreads();

    float s = 0.f;
    for (int i = tid; i < N4; i += 256) {
        float4 v = x4[i];
        s += expf(v.x - m) + expf(v.y - m) + expf(v.z - m) + expf(v.w - m);
    }
    red[tid] = s; __syncthreads();
    for (int ss = 128; ss > 0; ss >>= 1) {
        if (tid < ss) red[tid] += red[tid + ss];
        __syncthreads();
    }
    float lse = m + logf(red[0]);
    __syncthreads();

    for (int i = tid; i < N4; i += 256) {
        float4 v = x4[i];
        v.x -= lse; v.y -= lse; v.z -= lse; v.w -= lse;
        x4[i] = v;
    }
}

// ---------------------------------------------------------------------------
extern "C" void kernel_launch(void* const* d_in, const int* in_sizes, int n_in,
                              void* d_out, int out_size, void* d_ws, size_t ws_size,
                              hipStream_t stream)
{
    (void)in_sizes; (void)n_in; (void)out_size;

    const float* enc_hidden = (const float*)d_in[1];   // [L][B][H]; layer0 = enc_h
    const int*   target     = (const int*)  d_in[2];
    const float* emb        = (const float*)d_in[3];
    const float* w_ih0      = (const float*)d_in[4];   // [3H][2H]
    const float* w_hh0      = (const float*)d_in[5];   // [3H][H]
    const float* b_ih0      = (const float*)d_in[6];
    const float* b_hh0      = (const float*)d_in[7];
    const float* w_ih       = (const float*)d_in[8];   // [3][3H][H]
    const float* w_hh       = (const float*)d_in[9];
    const float* b_ih       = (const float*)d_in[10];
    const float* b_hh       = (const float*)d_in[11];
    const float* out_w      = (const float*)d_in[12];  // [V][H]
    const float* out_b      = (const float*)d_in[13];
    const float* l1_w       = (const float*)d_in[14];
    const float* l1_b       = (const float*)d_in[15];
    const float* l2_w       = (const float*)d_in[16];
    float* out = (float*)d_out;

    // --- workspace carve ---
    char* w = (char*)d_ws;
    auto alloc = [&](size_t bytes) -> char* {
        char* p = w; w += (bytes + 255) & ~(size_t)255; return p;
    };
    unsigned short* whh0_bf = (unsigned short*)alloc((size_t)N3H * H_ * 2);
    unsigned short* wih_bf  = (unsigned short*)alloc((size_t)3 * N3H * H_ * 2);
    unsigned short* whh_bf  = (unsigned short*)alloc((size_t)3 * N3H * H_ * 2);
    unsigned short* Ebf     = (unsigned short*)alloc((size_t)TB_ * H_ * 2);
    unsigned short* G0      = (unsigned short*)alloc((size_t)TB_ * N3H * 2);
    unsigned short* Hist    = (unsigned short*)alloc((size_t)TB_ * H_ * 2);
    unsigned short* hbf     = (unsigned short*)alloc((size_t)2 * L_ * B_ * H_ * 2);
    float*          Cbuf    = (float*)alloc(H_ * 4);
    float*          scores  = (float*)alloc(256);
    float*          wcC     = (float*)alloc(N3H * 4);
    unsigned*       flags   = (unsigned*)alloc((size_t)NBLK * FSTRIDE * 4);  // 14 KB
    unsigned*       done    = (unsigned*)alloc(256);
    size_t used = (size_t)(w - (char*)d_ws);
    unsigned short* outw_bf = nullptr;
    if (used + (size_t)V_ * H_ * 2 + 256 <= ws_size)
        outw_bf = (unsigned short*)alloc((size_t)V_ * H_ * 2);

    const size_t LBH = (size_t)L_ * B_ * H_;

    hipMemsetAsync(flags, 0, (size_t)NBLK * FSTRIDE * 4, stream);
    hipMemsetAsync(done, 0, 256, stream);

    // --- one-time precompute ---
    convbf_kernel<<<512, 256, 0, stream>>>(w_hh0, whh0_bf, N3H * H_ / 4);
    convbf_kernel<<<1024, 256, 0, stream>>>(w_ih, wih_bf, 3 * N3H * H_ / 4);
    convbf_kernel<<<1024, 256, 0, stream>>>(w_hh, whh_bf, 3 * N3H * H_ / 4);
    if (outw_bf)
        convbf_kernel<<<2048, 256, 0, stream>>>(out_w, outw_bf, V_ * H_ / 4);
    embed_bf_kernel<<<TB_, 256, 0, stream>>>(target, emb, Ebf);
    convbf_kernel<<<128, 256, 0, stream>>>(enc_hidden, hbf + LBH, (int)(LBH / 4));
    attn_pre_kernel<<<1, 256, 0, stream>>>(enc_hidden, l1_w, l1_b, l2_w, Cbuf, scores);
    wcc_kernel<<<N3H / 4, 256, 0, stream>>>(w_ih0, Cbuf, wcC);
    big_gemm_kernel<<<dim3(N3H / 128, TB_ / 128), 256, 0, stream>>>(
        w_ih0, 2 * H_, 0, Ebf, wcC, N3H, 0, G0);

    // --- persistent pipelined decode (one launch, 103 grid barriers) ---
    decode_kernel<<<NBLK, 512, 0, stream>>>(
        whh0_bf, wih_bf, whh_bf, G0, b_ih0, b_hh0, b_ih, b_hh,
        enc_hidden, hbf, Hist, out + (size_t)B_ * T_ * V_, flags, done);

    // --- deferred logits GEMM + log_softmax ---
    if (outw_bf)
        big_gemm_kernel<<<dim3(V_ / 128, TB_ / 128), 256, 0, stream>>>(
            outw_bf, H_, 1, Hist, out_b, V_, 1, out);
    else
        big_gemm_kernel<<<dim3(V_ / 128, TB_ / 128), 256, 0, stream>>>(
            out_w, H_, 0, Hist, out_b, V_, 1, out);
    logsoftmax_kernel<<<TB_, 256, 0, stream>>>(out);

    hipMemcpyAsync(out + (size_t)B_ * T_ * V_ + LBH, scores, B_ * 4,
                   hipMemcpyDeviceToDevice, stream);
}

// Round 5
// 3842.342 us; speedup vs baseline: 5.2631x; 1.5223x over previous
//
#include <hip/hip_runtime.h>
#include <hip/hip_bf16.h>
#include <math.h>

#define B_ 32
#define H_ 1024
#define V_ 32000
#define T_ 100
#define L_ 4
#define TB_ (T_*B_)      // 3200
#define N3H (3*H_)       // 3072
#define NBLK 224         // decode grid: 32 (layer0) + 3*64 (layers 1-3)
#define L0BLK 32
#define FSTRIDE 16       // flag padding: 16 uints = 64B per block
#define NGRP 7           // 224/32 done-relay groups

typedef __attribute__((ext_vector_type(8))) short bf16x8;
typedef __attribute__((ext_vector_type(4))) float f32x4;
typedef __attribute__((ext_vector_type(4))) unsigned short u16x4;

__device__ inline unsigned short f2bf(float f) {
    union { float f; unsigned u; } v; v.f = f;
    unsigned r = v.u + 0x7fff + ((v.u >> 16) & 1);   // RNE
    return (unsigned short)(r >> 16);
}
__device__ inline float bf2f(unsigned short u) {
    union { unsigned u; float f; } v; v.u = ((unsigned)u) << 16; return v.f;
}

// Device-coherent (L2-bypassing) 16B h-fragment load: two relaxed agent-scope
// 8B atomic loads. No cache-maintenance instructions are emitted for RELAXED.
__device__ inline bf16x8 ld_h16(const unsigned short* p) {
    union { unsigned long long u[2]; bf16x8 v; } r;
    r.u[0] = __hip_atomic_load((const unsigned long long*)p,
                               __ATOMIC_RELAXED, __HIP_MEMORY_SCOPE_AGENT);
    r.u[1] = __hip_atomic_load((const unsigned long long*)(p + 4),
                               __ATOMIC_RELAXED, __HIP_MEMORY_SCOPE_AGENT);
    return r.v;
}
__device__ inline void st_h2(unsigned short* p, unsigned short v) {
    __hip_atomic_store(p, v, __ATOMIC_RELAXED, __HIP_MEMORY_SCOPE_AGENT);
}

// ---------------------------------------------------------------------------
// fp32 -> bf16 contiguous convert (n4 = element count / 4)
// ---------------------------------------------------------------------------
__global__ __launch_bounds__(256) void convbf_kernel(
    const float* __restrict__ src, unsigned short* __restrict__ dst, int n4)
{
    for (int i = blockIdx.x * 256 + threadIdx.x; i < n4; i += gridDim.x * 256) {
        float4 v = ((const float4*)src)[i];
        u16x4 o; o.x = f2bf(v.x); o.y = f2bf(v.y); o.z = f2bf(v.z); o.w = f2bf(v.w);
        ((u16x4*)dst)[i] = o;
    }
}

// ---------------------------------------------------------------------------
// Ebf[t*B+b][h] = bf16(relu(emb[token(t,b)][h]))
// ---------------------------------------------------------------------------
__global__ __launch_bounds__(256) void embed_bf_kernel(
    const int* __restrict__ target, const float* __restrict__ emb,
    unsigned short* __restrict__ Ebf)
{
    int bid = blockIdx.x;                  // t*B+b
    int t = bid >> 5, b = bid & 31;
    int tok = (t == 0) ? 0 : target[b * T_ + (t - 1)];
    float4 v = ((const float4*)(emb + (size_t)tok * H_))[threadIdx.x];
    u16x4 o;
    o.x = f2bf(fmaxf(v.x, 0.f)); o.y = f2bf(fmaxf(v.y, 0.f));
    o.z = f2bf(fmaxf(v.z, 0.f)); o.w = f2bf(fmaxf(v.w, 0.f));
    ((u16x4*)(Ebf + (size_t)bid * H_))[threadIdx.x] = o;
}

// ---------------------------------------------------------------------------
// Attention collapse (step-invariant): scores = softmax_b(c_b), C = sum scores*enc_h
// ---------------------------------------------------------------------------
__global__ __launch_bounds__(256) void attn_pre_kernel(
    const float* __restrict__ enc_h, const float* __restrict__ l1_w,
    const float* __restrict__ l1_b, const float* __restrict__ l2_w,
    float* __restrict__ Cout, float* __restrict__ scores)
{
    __shared__ float L1h[96];
    __shared__ float sc[32];
    int tid = threadIdx.x, wv = tid >> 6, lane = tid & 63;
    for (int d = wv; d < 96; d += 4) {
        int b = d / 3, g = d - 3 * b;
        const float4* wp = (const float4*)(l1_w + (size_t)g * 2 * H_ + H_);
        const float4* ep = (const float4*)(enc_h + (size_t)b * H_);
        float s = 0.f;
        for (int q = lane; q < 256; q += 64) {
            float4 w4 = wp[q], e4 = ep[q];
            s += w4.x * e4.x + w4.y * e4.y + w4.z * e4.z + w4.w * e4.w;
        }
        for (int o = 32; o > 0; o >>= 1) s += __shfl_down(s, o);
        if (lane == 0) L1h[d] = s;
    }
    __syncthreads();
    if (tid < 32) {
        float cb = 0.f;
        for (int g = 0; g < 3; ++g) cb += l2_w[g] * (L1h[tid * 3 + g] + l1_b[g]);
        sc[tid] = cb;
    }
    __syncthreads();
    if (tid == 0) {
        float m = sc[0];
        for (int b = 1; b < 32; ++b) m = fmaxf(m, sc[b]);
        float s = 0.f;
        for (int b = 0; b < 32; ++b) { float e = expf(sc[b] - m); sc[b] = e; s += e; }
        float inv = 1.f / s;
        for (int b = 0; b < 32; ++b) { sc[b] *= inv; scores[b] = sc[b]; }
    }
    __syncthreads();
    float4 c = make_float4(0.f, 0.f, 0.f, 0.f);
    for (int b = 0; b < 32; ++b) {
        float4 e = ((const float4*)(enc_h + (size_t)b * H_))[tid];
        float ww = sc[b];
        c.x += ww * e.x; c.y += ww * e.y; c.z += ww * e.z; c.w += ww * e.w;
    }
    ((float4*)Cout)[tid] = c;
}

// ---------------------------------------------------------------------------
// wcC[n] = sum_k w_ih0[n][H+k] * C[k]
// ---------------------------------------------------------------------------
__global__ __launch_bounds__(256) void wcc_kernel(
    const float* __restrict__ w_ih0, const float* __restrict__ C,
    float* __restrict__ wcC)
{
    int row = blockIdx.x * 4 + (threadIdx.x >> 6);
    int lane = threadIdx.x & 63;
    const float4* wp = (const float4*)(w_ih0 + (size_t)row * 2 * H_ + H_);
    const float4* cp = (const float4*)C;
    float s = 0.f;
    for (int q = lane; q < 256; q += 64) {
        float4 w4 = wp[q], c4 = cp[q];
        s += w4.x * c4.x + w4.y * c4.y + w4.z * c4.z + w4.w * c4.w;
    }
    for (int o = 32; o > 0; o >>= 1) s += __shfl_down(s, o);
    if (lane == 0) wcC[row] = s;
}

// ---------------------------------------------------------------------------
// Big MFMA GEMM: out[row][col] = sum_k A[row][k]*Bb[col][k] + bias[row]
// ---------------------------------------------------------------------------
__global__ __launch_bounds__(256) void big_gemm_kernel(
    const void* __restrict__ Aptr, int lda, int abf,
    const unsigned short* __restrict__ Bb,
    const float* __restrict__ bias, int M, int outMode,
    void* __restrict__ outp)
{
    int tid = threadIdx.x, wv = tid >> 6, lane = tid & 63;
    int rlo = lane & 15, klane = (lane >> 4) * 8;
    int rowB = blockIdx.x * 128 + (wv >> 1) * 64;
    int colB = blockIdx.y * 128 + (wv & 1) * 64;
    const unsigned short* Ab = (const unsigned short*)Aptr;
    const float* Af = (const float*)Aptr;

    f32x4 acc[4][4];
    #pragma unroll
    for (int i = 0; i < 4; ++i)
        #pragma unroll
        for (int j = 0; j < 4; ++j) acc[i][j] = (f32x4){0.f, 0.f, 0.f, 0.f};

    for (int k0 = 0; k0 < H_; k0 += 32) {
        bf16x8 bfrag[4];
        #pragma unroll
        for (int ci = 0; ci < 4; ++ci) {
            int col = colB + ci * 16 + rlo;
            bfrag[ci] = *(const bf16x8*)(Bb + (size_t)col * H_ + k0 + klane);
        }
        #pragma unroll
        for (int ri = 0; ri < 4; ++ri) {
            int row = rowB + ri * 16 + rlo;
            bf16x8 af;
            if (abf) {
                af = *(const bf16x8*)(Ab + (size_t)row * lda + k0 + klane);
            } else {
                const float* ap = Af + (size_t)row * lda + k0 + klane;
                float4 x0 = *(const float4*)ap, x1 = *(const float4*)(ap + 4);
                af[0] = (short)f2bf(x0.x); af[1] = (short)f2bf(x0.y);
                af[2] = (short)f2bf(x0.z); af[3] = (short)f2bf(x0.w);
                af[4] = (short)f2bf(x1.x); af[5] = (short)f2bf(x1.y);
                af[6] = (short)f2bf(x1.z); af[7] = (short)f2bf(x1.w);
            }
            #pragma unroll
            for (int ci = 0; ci < 4; ++ci)
                acc[ri][ci] = __builtin_amdgcn_mfma_f32_16x16x32_bf16(
                    af, bfrag[ci], acc[ri][ci], 0, 0, 0);
        }
    }

    int rowoff = (lane >> 4) * 4;
    #pragma unroll
    for (int ri = 0; ri < 4; ++ri) {
        int row = rowB + ri * 16 + rowoff;
        float4 bs = *(const float4*)(bias + row);
        #pragma unroll
        for (int ci = 0; ci < 4; ++ci) {
            int col = colB + ci * 16 + rlo;
            float4 v;
            v.x = acc[ri][ci][0] + bs.x; v.y = acc[ri][ci][1] + bs.y;
            v.z = acc[ri][ci][2] + bs.z; v.w = acc[ri][ci][3] + bs.w;
            if (outMode == 1) {
                int tt = col >> 5, b = col & 31;
                *(float4*)((float*)outp + ((size_t)b * T_ + tt) * V_ + row) = v;
            } else {
                u16x4 o; o.x = f2bf(v.x); o.y = f2bf(v.y);
                o.z = f2bf(v.z); o.w = f2bf(v.w);
                *(u16x4*)((unsigned short*)outp + (size_t)col * M + row) = o;
            }
        }
    }
}

// ---------------------------------------------------------------------------
// Fence-free grid barrier. ALL atomics RELAXED agent-scope (no buffer_inv /
// buffer_wbl2). Ordering: __syncthreads() drains vmcnt(0) for every wave, so
// all write-through h stores are globally visible before the flag store.
// done fan-out over NGRP lines caps pollers/line at 32.
// ---------------------------------------------------------------------------
__device__ inline void grid_bar3(unsigned* flags, unsigned* doneg, unsigned round)
{
    __syncthreads();                       // drains vmcnt(0) for all waves
    if (threadIdx.x == 0) {
        asm volatile("s_waitcnt vmcnt(0)" ::: "memory");
        __hip_atomic_store(&flags[(size_t)blockIdx.x * FSTRIDE], round,
                           __ATOMIC_RELAXED, __HIP_MEMORY_SCOPE_AGENT);
    }
    if (blockIdx.x == 0) {
        int ok = (threadIdx.x >= NBLK) ? 1 : 0;
        do {
            if (!ok)
                ok = (__hip_atomic_load(&flags[(size_t)threadIdx.x * FSTRIDE],
                                        __ATOMIC_RELAXED, __HIP_MEMORY_SCOPE_AGENT) >= round);
        } while (!__syncthreads_and(ok));
        if (threadIdx.x < NGRP)
            __hip_atomic_store(&doneg[(size_t)threadIdx.x * FSTRIDE], round,
                               __ATOMIC_RELAXED, __HIP_MEMORY_SCOPE_AGENT);
    } else if (threadIdx.x == 0) {
        unsigned* dl = &doneg[(size_t)(blockIdx.x >> 5) * FSTRIDE];
        while (__hip_atomic_load(dl, __ATOMIC_RELAXED, __HIP_MEMORY_SCOPE_AGENT) < round)
            __builtin_amdgcn_s_sleep(2);
    }
    __syncthreads();
}

// ---------------------------------------------------------------------------
// Persistent pipelined decode. Block -> (layer, feature slice).
//   layer 0: 32 blocks, 32 features each (gh via whh0; gi from G0)
//   layers 1-3: 64 blocks each, 16 features (gi + gh)
// Weights pinned in registers (96 regs/lane). h exchange via device-coherent
// (L2-bypass) relaxed atomics; barrier is fence-free.
// ---------------------------------------------------------------------------
__global__ __launch_bounds__(512, 2) void decode_kernel(
    const unsigned short* __restrict__ whh0_bf,   // [3H][H]
    const unsigned short* __restrict__ wih_bf,    // [3][3H][H]
    const unsigned short* __restrict__ whh_bf,    // [3][3H][H]
    const unsigned short* __restrict__ G0,        // [TB][3H] bf16
    const float* __restrict__ b_ih0, const float* __restrict__ b_hh0,
    const float* __restrict__ b_ih,  const float* __restrict__ b_hh,
    const float* __restrict__ enc_hidden,         // [L][B][H] fp32
    unsigned short* __restrict__ hbf,             // [2][L][B][H] bf16
    unsigned short* __restrict__ Hist,            // [TB][H] bf16
    float* __restrict__ hid_out,                  // d_out + B*T*V
    unsigned* __restrict__ flags, unsigned* __restrict__ doneg)
{
    __shared__ float sacc[6][4][16][34];          // rg, kc, row, col
    const int tid = threadIdx.x;
    const int wv = tid >> 6, lane = tid & 63;
    const int rlo = lane & 15, klane = (lane >> 4) * 8;
    const int rowoff = (lane >> 4) * 4;
    const int bid = blockIdx.x;

    int layer, f0;
    if (bid < L0BLK) { layer = 0; f0 = bid << 5; }
    else { int r = bid - L0BLK; layer = 1 + (r >> 6); f0 = (r & 63) << 4; }

    const unsigned short* Wih_l = (layer >= 1) ? wih_bf + (size_t)(layer - 1) * N3H * H_ : nullptr;
    const unsigned short* Whh_l = (layer >= 1) ? whh_bf + (size_t)(layer - 1) * N3H * H_ : whh0_bf;

    // ---- weight preload into registers ----
    bf16x8 wreg[3][8];
    int rgv[3], kcv[3];
    #pragma unroll
    for (int i = 0; i < 3; ++i) {
        int q = wv * 3 + i;                 // 0..23
        int rg = q >> 2, kc = q & 3;
        rgv[i] = rg; kcv[i] = kc;
        int wrow; const unsigned short* Wm;
        if (layer == 0)      { wrow = (rg >> 1) * H_ + f0 + (rg & 1) * 16; Wm = Whh_l; }
        else if (rg < 3)     { wrow = rg * H_ + f0;        Wm = Wih_l; }
        else                 { wrow = (rg - 3) * H_ + f0;  Wm = Whh_l; }
        const unsigned short* p = Wm + (size_t)(wrow + rlo) * H_ + kc * 256 + klane;
        #pragma unroll
        for (int s = 0; s < 8; ++s) wreg[i][s] = *(const bf16x8*)(p + s * 32);
    }

    // ---- bias + hold-state registers ----
    const float* bihp = (layer == 0) ? b_ih0 : b_ih + (size_t)(layer - 1) * N3H;
    const float* bhhp = (layer == 0) ? b_hh0 : b_hh + (size_t)(layer - 1) * N3H;
    int jj, eb0;
    float hold0, hold1 = 0.f;
    if (layer == 0) {
        jj = f0 + (tid & 31);
        eb0 = tid >> 5;                     // batch for rep0; rep1 = eb0+16
        hold0 = enc_hidden[(size_t)eb0 * H_ + jj];
        hold1 = enc_hidden[(size_t)(eb0 + 16) * H_ + jj];
    } else {
        jj = f0 + (tid >> 5);
        eb0 = tid & 31;
        hold0 = enc_hidden[(size_t)layer * B_ * H_ + (size_t)eb0 * H_ + jj];
    }
    const float bir = bihp[jj], biz = bihp[H_ + jj], bin_ = bihp[2 * H_ + jj];
    const float bhr = bhhp[jj], bhz = bhhp[H_ + jj], bhn = bhhp[2 * H_ + jj];

    const size_t BH = (size_t)B_ * H_;

    for (int c = 0; c < T_ + L_ - 1; ++c) {
        int t = c - layer;
        if (t >= 0 && t < T_) {
            int pw = t & 1, pr = pw ^ 1;
            const unsigned short* hown  = hbf + ((size_t)pr * L_ + layer) * BH;
            const unsigned short* hprev = (layer > 0)
                ? hbf + ((size_t)pw * L_ + (layer - 1)) * BH : nullptr;

            f32x4 acc[3][2];
            #pragma unroll
            for (int i = 0; i < 3; ++i) {
                acc[i][0] = (f32x4){0.f, 0.f, 0.f, 0.f};
                acc[i][1] = (f32x4){0.f, 0.f, 0.f, 0.f};
            }

            #pragma unroll
            for (int i = 0; i < 3; ++i) {
                const unsigned short* hsrc = (layer == 0 || rgv[i] >= 3) ? hown : hprev;
                const unsigned short* hp = hsrc + (size_t)rlo * H_ + kcv[i] * 256 + klane;
                #pragma unroll
                for (int s = 0; s < 8; ++s) {
                    bf16x8 b0 = ld_h16(hp + s * 32);
                    bf16x8 b1 = ld_h16(hp + 16 * H_ + s * 32);
                    acc[i][0] = __builtin_amdgcn_mfma_f32_16x16x32_bf16(wreg[i][s], b0, acc[i][0], 0, 0, 0);
                    acc[i][1] = __builtin_amdgcn_mfma_f32_16x16x32_bf16(wreg[i][s], b1, acc[i][1], 0, 0, 0);
                }
            }

            #pragma unroll
            for (int i = 0; i < 3; ++i)
                #pragma unroll
                for (int r = 0; r < 4; ++r) {
                    sacc[rgv[i]][kcv[i]][rowoff + r][rlo]      = acc[i][0][r];
                    sacc[rgv[i]][kcv[i]][rowoff + r][16 + rlo] = acc[i][1][r];
                }
            __syncthreads();

            if (layer > 0) {
                int f = tid >> 5, b = tid & 31;
                float ir = bir, iz = biz, in_ = bin_;
                float hr = bhr, hz = bhz, hn = bhn;
                #pragma unroll
                for (int kc = 0; kc < 4; ++kc) {
                    ir += sacc[0][kc][f][b]; iz += sacc[1][kc][f][b]; in_ += sacc[2][kc][f][b];
                    hr += sacc[3][kc][f][b]; hz += sacc[4][kc][f][b]; hn += sacc[5][kc][f][b];
                }
                float r = 1.f / (1.f + expf(-(ir + hr)));
                float z = 1.f / (1.f + expf(-(iz + hz)));
                float n = tanhf(in_ + r * hn);
                float hnew = (1.f - z) * n + z * hold0;
                hold0 = hnew;
                unsigned short hb16 = f2bf(hnew);
                st_h2(&hbf[((size_t)pw * L_ + layer) * BH + (size_t)b * H_ + jj], hb16);
                if (layer == L_ - 1) Hist[((size_t)t * B_ + b) * H_ + jj] = hb16;
                if (t == T_ - 1) hid_out[(size_t)layer * BH + (size_t)b * H_ + jj] = hnew;
            } else {
                int fi = tid & 31;
                int rghalf = fi >> 4, fr = fi & 15;
                {
                    int b = eb0;
                    const unsigned short* g0p = G0 + ((size_t)t * B_ + b) * N3H;
                    float ir = bf2f(g0p[jj]) + bir;
                    float iz = bf2f(g0p[H_ + jj]) + biz;
                    float in_ = bf2f(g0p[2 * H_ + jj]) + bin_;
                    float hr = bhr, hz = bhz, hn = bhn;
                    #pragma unroll
                    for (int kc = 0; kc < 4; ++kc) {
                        hr += sacc[rghalf][kc][fr][b];
                        hz += sacc[2 + rghalf][kc][fr][b];
                        hn += sacc[4 + rghalf][kc][fr][b];
                    }
                    float r = 1.f / (1.f + expf(-(ir + hr)));
                    float z = 1.f / (1.f + expf(-(iz + hz)));
                    float n = tanhf(in_ + r * hn);
                    float hnew = (1.f - z) * n + z * hold0;
                    hold0 = hnew;
                    st_h2(&hbf[((size_t)pw * L_) * BH + (size_t)b * H_ + jj], f2bf(hnew));
                    if (t == T_ - 1) hid_out[(size_t)b * H_ + jj] = hnew;
                }
                {
                    int b = eb0 + 16;
                    const unsigned short* g0p = G0 + ((size_t)t * B_ + b) * N3H;
                    float ir = bf2f(g0p[jj]) + bir;
                    float iz = bf2f(g0p[H_ + jj]) + biz;
                    float in_ = bf2f(g0p[2 * H_ + jj]) + bin_;
                    float hr = bhr, hz = bhz, hn = bhn;
                    #pragma unroll
                    for (int kc = 0; kc < 4; ++kc) {
                        hr += sacc[rghalf][kc][fr][b];
                        hz += sacc[2 + rghalf][kc][fr][b];
                        hn += sacc[4 + rghalf][kc][fr][b];
                    }
                    float r = 1.f / (1.f + expf(-(ir + hr)));
                    float z = 1.f / (1.f + expf(-(iz + hz)));
                    float n = tanhf(in_ + r * hn);
                    float hnew = (1.f - z) * n + z * hold1;
                    hold1 = hnew;
                    st_h2(&hbf[((size_t)pw * L_) * BH + (size_t)b * H_ + jj], f2bf(hnew));
                    if (t == T_ - 1) hid_out[(size_t)b * H_ + jj] = hnew;
                }
            }
        }
        grid_bar3(flags, doneg, (unsigned)(c + 1));
    }
}

// ---------------------------------------------------------------------------
// In-place log_softmax over rows of V_ (float4 vectorized)
// ---------------------------------------------------------------------------
__global__ __launch_bounds__(256) void logsoftmax_kernel(float* __restrict__ dout)
{
    __shared__ float red[256];
    float4* x4 = (float4*)(dout + (size_t)blockIdx.x * V_);
    const int N4 = V_ / 4;
    int tid = threadIdx.x;

    float m = -INFINITY;
    for (int i = tid; i < N4; i += 256) {
        float4 v = x4[i];
        m = fmaxf(m, fmaxf(fmaxf(v.x, v.y), fmaxf(v.z, v.w)));
    }
    red[tid] = m; __syncthreads();
    for (int s = 128; s > 0; s >>= 1) {
        if (tid < s) red[tid] = fmaxf(red[tid], red[tid + s]);
        __syncthreads();
    }
    m = red[0]; __syncthreads();

    float s = 0.f;
    for (int i = tid; i < N4; i += 256) {
        float4 v = x4[i];
        s += expf(v.x - m) + expf(v.y - m) + expf(v.z - m) + expf(v.w - m);
    }
    red[tid] = s; __syncthreads();
    for (int ss = 128; ss > 0; ss >>= 1) {
        if (tid < ss) red[tid] += red[tid + ss];
        __syncthreads();
    }
    float lse = m + logf(red[0]);
    __syncthreads();

    for (int i = tid; i < N4; i += 256) {
        float4 v = x4[i];
        v.x -= lse; v.y -= lse; v.z -= lse; v.w -= lse;
        x4[i] = v;
    }
}

// ---------------------------------------------------------------------------
extern "C" void kernel_launch(void* const* d_in, const int* in_sizes, int n_in,
                              void* d_out, int out_size, void* d_ws, size_t ws_size,
                              hipStream_t stream)
{
    (void)in_sizes; (void)n_in; (void)out_size;

    const float* enc_hidden = (const float*)d_in[1];   // [L][B][H]; layer0 = enc_h
    const int*   target     = (const int*)  d_in[2];
    const float* emb        = (const float*)d_in[3];
    const float* w_ih0      = (const float*)d_in[4];   // [3H][2H]
    const float* w_hh0      = (const float*)d_in[5];   // [3H][H]
    const float* b_ih0      = (const float*)d_in[6];
    const float* b_hh0      = (const float*)d_in[7];
    const float* w_ih       = (const float*)d_in[8];   // [3][3H][H]
    const float* w_hh       = (const float*)d_in[9];
    const float* b_ih       = (const float*)d_in[10];
    const float* b_hh       = (const float*)d_in[11];
    const float* out_w      = (const float*)d_in[12];  // [V][H]
    const float* out_b      = (const float*)d_in[13];
    const float* l1_w       = (const float*)d_in[14];
    const float* l1_b       = (const float*)d_in[15];
    const float* l2_w       = (const float*)d_in[16];
    float* out = (float*)d_out;

    // --- workspace carve ---
    char* w = (char*)d_ws;
    auto alloc = [&](size_t bytes) -> char* {
        char* p = w; w += (bytes + 255) & ~(size_t)255; return p;
    };
    unsigned short* whh0_bf = (unsigned short*)alloc((size_t)N3H * H_ * 2);
    unsigned short* wih_bf  = (unsigned short*)alloc((size_t)3 * N3H * H_ * 2);
    unsigned short* whh_bf  = (unsigned short*)alloc((size_t)3 * N3H * H_ * 2);
    unsigned short* Ebf     = (unsigned short*)alloc((size_t)TB_ * H_ * 2);
    unsigned short* G0      = (unsigned short*)alloc((size_t)TB_ * N3H * 2);
    unsigned short* Hist    = (unsigned short*)alloc((size_t)TB_ * H_ * 2);
    unsigned short* hbf     = (unsigned short*)alloc((size_t)2 * L_ * B_ * H_ * 2);
    float*          Cbuf    = (float*)alloc(H_ * 4);
    float*          scores  = (float*)alloc(256);
    float*          wcC     = (float*)alloc(N3H * 4);
    unsigned*       flags   = (unsigned*)alloc((size_t)NBLK * FSTRIDE * 4);  // 14 KB
    unsigned*       doneg   = (unsigned*)alloc((size_t)(NGRP + 1) * FSTRIDE * 4);
    size_t used = (size_t)(w - (char*)d_ws);
    unsigned short* outw_bf = nullptr;
    if (used + (size_t)V_ * H_ * 2 + 256 <= ws_size)
        outw_bf = (unsigned short*)alloc((size_t)V_ * H_ * 2);

    const size_t LBH = (size_t)L_ * B_ * H_;

    hipMemsetAsync(flags, 0, (size_t)NBLK * FSTRIDE * 4, stream);
    hipMemsetAsync(doneg, 0, (size_t)(NGRP + 1) * FSTRIDE * 4, stream);

    // --- one-time precompute ---
    convbf_kernel<<<512, 256, 0, stream>>>(w_hh0, whh0_bf, N3H * H_ / 4);
    convbf_kernel<<<1024, 256, 0, stream>>>(w_ih, wih_bf, 3 * N3H * H_ / 4);
    convbf_kernel<<<1024, 256, 0, stream>>>(w_hh, whh_bf, 3 * N3H * H_ / 4);
    if (outw_bf)
        convbf_kernel<<<2048, 256, 0, stream>>>(out_w, outw_bf, V_ * H_ / 4);
    embed_bf_kernel<<<TB_, 256, 0, stream>>>(target, emb, Ebf);
    convbf_kernel<<<128, 256, 0, stream>>>(enc_hidden, hbf + LBH, (int)(LBH / 4));
    attn_pre_kernel<<<1, 256, 0, stream>>>(enc_hidden, l1_w, l1_b, l2_w, Cbuf, scores);
    wcc_kernel<<<N3H / 4, 256, 0, stream>>>(w_ih0, Cbuf, wcC);
    big_gemm_kernel<<<dim3(N3H / 128, TB_ / 128), 256, 0, stream>>>(
        w_ih0, 2 * H_, 0, Ebf, wcC, N3H, 0, G0);

    // --- persistent pipelined decode (one launch, 103 grid barriers) ---
    decode_kernel<<<NBLK, 512, 0, stream>>>(
        whh0_bf, wih_bf, whh_bf, G0, b_ih0, b_hh0, b_ih, b_hh,
        enc_hidden, hbf, Hist, out + (size_t)B_ * T_ * V_, flags, doneg);

    // --- deferred logits GEMM + log_softmax ---
    if (outw_bf)
        big_gemm_kernel<<<dim3(V_ / 128, TB_ / 128), 256, 0, stream>>>(
            outw_bf, H_, 1, Hist, out_b, V_, 1, out);
    else
        big_gemm_kernel<<<dim3(V_ / 128, TB_ / 128), 256, 0, stream>>>(
            out_w, H_, 0, Hist, out_b, V_, 1, out);
    logsoftmax_kernel<<<TB_, 256, 0, stream>>>(out);

    hipMemcpyAsync(out + (size_t)B_ * T_ * V_ + LBH, scores, B_ * 4,
                   hipMemcpyDeviceToDevice, stream);
}

// Round 6
// 2388.316 us; speedup vs baseline: 8.4673x; 1.6088x over previous
//
#include <hip/hip_runtime.h>
#include <hip/hip_bf16.h>
#include <math.h>

#define B_ 32
#define H_ 1024
#define V_ 32000
#define T_ 100
#define L_ 4
#define TB_ (T_*B_)      // 3200
#define N3H (3*H_)       // 3072
#define NBLK 224         // decode grid: 32 (layer0) + 3*64 (layers 1-3)
#define L0BLK 32
#define FSTRIDE 16       // flag padding: 16 uints = 64B per block

typedef __attribute__((ext_vector_type(8))) short bf16x8;
typedef __attribute__((ext_vector_type(4))) float f32x4;
typedef __attribute__((ext_vector_type(4))) unsigned short u16x4;

__device__ inline unsigned short f2bf(float f) {
    union { float f; unsigned u; } v; v.f = f;
    unsigned r = v.u + 0x7fff + ((v.u >> 16) & 1);   // RNE
    return (unsigned short)(r >> 16);
}
__device__ inline float bf2f(unsigned short u) {
    union { unsigned u; float f; } v; v.u = ((unsigned)u) << 16; return v.f;
}

// Device-coherent (L2-bypassing) 16B h-fragment load: two relaxed agent-scope
// 8B atomic loads (no cache-maintenance emitted for RELAXED).
__device__ inline bf16x8 ld_h16(const unsigned short* p) {
    union { unsigned long long u[2]; bf16x8 v; } r;
    r.u[0] = __hip_atomic_load((const unsigned long long*)p,
                               __ATOMIC_RELAXED, __HIP_MEMORY_SCOPE_AGENT);
    r.u[1] = __hip_atomic_load((const unsigned long long*)(p + 4),
                               __ATOMIC_RELAXED, __HIP_MEMORY_SCOPE_AGENT);
    return r.v;
}
__device__ inline void st_h2(unsigned short* p, unsigned short v) {
    __hip_atomic_store(p, v, __ATOMIC_RELAXED, __HIP_MEMORY_SCOPE_AGENT);
}

// ---------------------------------------------------------------------------
// fp32 -> bf16 contiguous convert (n4 = element count / 4)
// ---------------------------------------------------------------------------
__global__ __launch_bounds__(256) void convbf_kernel(
    const float* __restrict__ src, unsigned short* __restrict__ dst, int n4)
{
    for (int i = blockIdx.x * 256 + threadIdx.x; i < n4; i += gridDim.x * 256) {
        float4 v = ((const float4*)src)[i];
        u16x4 o; o.x = f2bf(v.x); o.y = f2bf(v.y); o.z = f2bf(v.z); o.w = f2bf(v.w);
        ((u16x4*)dst)[i] = o;
    }
}

// ---------------------------------------------------------------------------
// Ebf[t*B+b][h] = bf16(relu(emb[token(t,b)][h]))
// ---------------------------------------------------------------------------
__global__ __launch_bounds__(256) void embed_bf_kernel(
    const int* __restrict__ target, const float* __restrict__ emb,
    unsigned short* __restrict__ Ebf)
{
    int bid = blockIdx.x;                  // t*B+b
    int t = bid >> 5, b = bid & 31;
    int tok = (t == 0) ? 0 : target[b * T_ + (t - 1)];
    float4 v = ((const float4*)(emb + (size_t)tok * H_))[threadIdx.x];
    u16x4 o;
    o.x = f2bf(fmaxf(v.x, 0.f)); o.y = f2bf(fmaxf(v.y, 0.f));
    o.z = f2bf(fmaxf(v.z, 0.f)); o.w = f2bf(fmaxf(v.w, 0.f));
    ((u16x4*)(Ebf + (size_t)bid * H_))[threadIdx.x] = o;
}

// ---------------------------------------------------------------------------
// Attention collapse (step-invariant): scores = softmax_b(c_b), C = sum scores*enc_h
// ---------------------------------------------------------------------------
__global__ __launch_bounds__(256) void attn_pre_kernel(
    const float* __restrict__ enc_h, const float* __restrict__ l1_w,
    const float* __restrict__ l1_b, const float* __restrict__ l2_w,
    float* __restrict__ Cout, float* __restrict__ scores)
{
    __shared__ float L1h[96];
    __shared__ float sc[32];
    int tid = threadIdx.x, wv = tid >> 6, lane = tid & 63;
    for (int d = wv; d < 96; d += 4) {
        int b = d / 3, g = d - 3 * b;
        const float4* wp = (const float4*)(l1_w + (size_t)g * 2 * H_ + H_);
        const float4* ep = (const float4*)(enc_h + (size_t)b * H_);
        float s = 0.f;
        for (int q = lane; q < 256; q += 64) {
            float4 w4 = wp[q], e4 = ep[q];
            s += w4.x * e4.x + w4.y * e4.y + w4.z * e4.z + w4.w * e4.w;
        }
        for (int o = 32; o > 0; o >>= 1) s += __shfl_down(s, o);
        if (lane == 0) L1h[d] = s;
    }
    __syncthreads();
    if (tid < 32) {
        float cb = 0.f;
        for (int g = 0; g < 3; ++g) cb += l2_w[g] * (L1h[tid * 3 + g] + l1_b[g]);
        sc[tid] = cb;
    }
    __syncthreads();
    if (tid == 0) {
        float m = sc[0];
        for (int b = 1; b < 32; ++b) m = fmaxf(m, sc[b]);
        float s = 0.f;
        for (int b = 0; b < 32; ++b) { float e = expf(sc[b] - m); sc[b] = e; s += e; }
        float inv = 1.f / s;
        for (int b = 0; b < 32; ++b) { sc[b] *= inv; scores[b] = sc[b]; }
    }
    __syncthreads();
    float4 c = make_float4(0.f, 0.f, 0.f, 0.f);
    for (int b = 0; b < 32; ++b) {
        float4 e = ((const float4*)(enc_h + (size_t)b * H_))[tid];
        float ww = sc[b];
        c.x += ww * e.x; c.y += ww * e.y; c.z += ww * e.z; c.w += ww * e.w;
    }
    ((float4*)Cout)[tid] = c;
}

// ---------------------------------------------------------------------------
// wcC[n] = sum_k w_ih0[n][H+k] * C[k]
// ---------------------------------------------------------------------------
__global__ __launch_bounds__(256) void wcc_kernel(
    const float* __restrict__ w_ih0, const float* __restrict__ C,
    float* __restrict__ wcC)
{
    int row = blockIdx.x * 4 + (threadIdx.x >> 6);
    int lane = threadIdx.x & 63;
    const float4* wp = (const float4*)(w_ih0 + (size_t)row * 2 * H_ + H_);
    const float4* cp = (const float4*)C;
    float s = 0.f;
    for (int q = lane; q < 256; q += 64) {
        float4 w4 = wp[q], c4 = cp[q];
        s += w4.x * c4.x + w4.y * c4.y + w4.z * c4.z + w4.w * c4.w;
    }
    for (int o = 32; o > 0; o >>= 1) s += __shfl_down(s, o);
    if (lane == 0) wcC[row] = s;
}

// ---------------------------------------------------------------------------
// Big MFMA GEMM: out[row][col] = sum_k A[row][k]*Bb[col][k] + bias[row]
// ---------------------------------------------------------------------------
__global__ __launch_bounds__(256) void big_gemm_kernel(
    const void* __restrict__ Aptr, int lda, int abf,
    const unsigned short* __restrict__ Bb,
    const float* __restrict__ bias, int M, int outMode,
    void* __restrict__ outp)
{
    int tid = threadIdx.x, wv = tid >> 6, lane = tid & 63;
    int rlo = lane & 15, klane = (lane >> 4) * 8;
    int rowB = blockIdx.x * 128 + (wv >> 1) * 64;
    int colB = blockIdx.y * 128 + (wv & 1) * 64;
    const unsigned short* Ab = (const unsigned short*)Aptr;
    const float* Af = (const float*)Aptr;

    f32x4 acc[4][4];
    #pragma unroll
    for (int i = 0; i < 4; ++i)
        #pragma unroll
        for (int j = 0; j < 4; ++j) acc[i][j] = (f32x4){0.f, 0.f, 0.f, 0.f};

    for (int k0 = 0; k0 < H_; k0 += 32) {
        bf16x8 bfrag[4];
        #pragma unroll
        for (int ci = 0; ci < 4; ++ci) {
            int col = colB + ci * 16 + rlo;
            bfrag[ci] = *(const bf16x8*)(Bb + (size_t)col * H_ + k0 + klane);
        }
        #pragma unroll
        for (int ri = 0; ri < 4; ++ri) {
            int row = rowB + ri * 16 + rlo;
            bf16x8 af;
            if (abf) {
                af = *(const bf16x8*)(Ab + (size_t)row * lda + k0 + klane);
            } else {
                const float* ap = Af + (size_t)row * lda + k0 + klane;
                float4 x0 = *(const float4*)ap, x1 = *(const float4*)(ap + 4);
                af[0] = (short)f2bf(x0.x); af[1] = (short)f2bf(x0.y);
                af[2] = (short)f2bf(x0.z); af[3] = (short)f2bf(x0.w);
                af[4] = (short)f2bf(x1.x); af[5] = (short)f2bf(x1.y);
                af[6] = (short)f2bf(x1.z); af[7] = (short)f2bf(x1.w);
            }
            #pragma unroll
            for (int ci = 0; ci < 4; ++ci)
                acc[ri][ci] = __builtin_amdgcn_mfma_f32_16x16x32_bf16(
                    af, bfrag[ci], acc[ri][ci], 0, 0, 0);
        }
    }

    int rowoff = (lane >> 4) * 4;
    #pragma unroll
    for (int ri = 0; ri < 4; ++ri) {
        int row = rowB + ri * 16 + rowoff;
        float4 bs = *(const float4*)(bias + row);
        #pragma unroll
        for (int ci = 0; ci < 4; ++ci) {
            int col = colB + ci * 16 + rlo;
            float4 v;
            v.x = acc[ri][ci][0] + bs.x; v.y = acc[ri][ci][1] + bs.y;
            v.z = acc[ri][ci][2] + bs.z; v.w = acc[ri][ci][3] + bs.w;
            if (outMode == 1) {
                int tt = col >> 5, b = col & 31;
                *(float4*)((float*)outp + ((size_t)b * T_ + tt) * V_ + row) = v;
            } else {
                u16x4 o; o.x = f2bf(v.x); o.y = f2bf(v.y);
                o.z = f2bf(v.z); o.w = f2bf(v.w);
                *(u16x4*)((unsigned short*)outp + (size_t)col * M + row) = o;
            }
        }
    }
}

// ---------------------------------------------------------------------------
// Fence-free direct-poll grid barrier: every block stores its padded flag
// (relaxed agent scope) and polls ALL flags itself (224 watcher threads +
// __syncthreads_and). No relay hops, no cache-maintenance instructions.
// ---------------------------------------------------------------------------
__device__ inline void grid_bar4(unsigned* flags, unsigned round)
{
    __syncthreads();                       // all waves' stores issued
    if (threadIdx.x == 0) {
        asm volatile("s_waitcnt vmcnt(0)" ::: "memory");
        __hip_atomic_store(&flags[(size_t)blockIdx.x * FSTRIDE], round,
                           __ATOMIC_RELAXED, __HIP_MEMORY_SCOPE_AGENT);
    }
    int ok = (threadIdx.x >= NBLK) ? 1 : 0;
    do {
        if (!ok)
            ok = (__hip_atomic_load(&flags[(size_t)threadIdx.x * FSTRIDE],
                                    __ATOMIC_RELAXED, __HIP_MEMORY_SCOPE_AGENT) >= round);
    } while (!__syncthreads_and(ok));
}

// ---------------------------------------------------------------------------
// Persistent pipelined decode. Block -> (layer, feature slice).
//   layer 0: 32 blocks, 32 features each (gh via whh0; gi from G0)
//   layers 1-3: 64 blocks each, 16 features (gi + gh)
// Wave wv owns (srcgrp = wv>>2, kc = wv&3), tasks rg = srcgrp*3+{0,1,2}:
// the 3 MFMAs share one B-fragment load (same source, same kc) -> 32
// device-scope loads/thread instead of 96.
// ---------------------------------------------------------------------------
__global__ __launch_bounds__(512, 2) void decode_kernel(
    const unsigned short* __restrict__ whh0_bf,   // [3H][H]
    const unsigned short* __restrict__ wih_bf,    // [3][3H][H]
    const unsigned short* __restrict__ whh_bf,    // [3][3H][H]
    const unsigned short* __restrict__ G0,        // [TB][3H] bf16
    const float* __restrict__ b_ih0, const float* __restrict__ b_hh0,
    const float* __restrict__ b_ih,  const float* __restrict__ b_hh,
    const float* __restrict__ enc_hidden,         // [L][B][H] fp32
    unsigned short* __restrict__ hbf,             // [2][L][B][H] bf16
    unsigned short* __restrict__ Hist,            // [TB][H] bf16
    float* __restrict__ hid_out,                  // d_out + B*T*V
    unsigned* __restrict__ flags)
{
    __shared__ float sacc[6][4][16][34];          // rg, kc, row(f), col(b)
    const int tid = threadIdx.x;
    const int wv = tid >> 6, lane = tid & 63;
    const int rlo = lane & 15, klane = (lane >> 4) * 8;
    const int rowoff = (lane >> 4) * 4;
    const int bid = blockIdx.x;

    int layer, f0;
    if (bid < L0BLK) { layer = 0; f0 = bid << 5; }
    else { int r = bid - L0BLK; layer = 1 + (r >> 6); f0 = (r & 63) << 4; }

    const unsigned short* Wih_l = (layer >= 1) ? wih_bf + (size_t)(layer - 1) * N3H * H_ : nullptr;
    const unsigned short* Whh_l = (layer >= 1) ? whh_bf + (size_t)(layer - 1) * N3H * H_ : whh0_bf;

    // ---- task assignment: shared (source, kc) per wave ----
    const int kc = wv & 3, srcgrp = wv >> 2;

    // ---- weight preload into registers ----
    bf16x8 wreg[3][8];
    int rgv[3];
    #pragma unroll
    for (int i = 0; i < 3; ++i) {
        int rg = srcgrp * 3 + i;
        rgv[i] = rg;
        int wrow; const unsigned short* Wm;
        if (layer == 0)      { wrow = (rg >> 1) * H_ + f0 + (rg & 1) * 16; Wm = Whh_l; }
        else if (rg < 3)     { wrow = rg * H_ + f0;        Wm = Wih_l; }
        else                 { wrow = (rg - 3) * H_ + f0;  Wm = Whh_l; }
        const unsigned short* p = Wm + (size_t)(wrow + rlo) * H_ + kc * 256 + klane;
        #pragma unroll
        for (int s = 0; s < 8; ++s) wreg[i][s] = *(const bf16x8*)(p + s * 32);
    }

    // ---- bias + hold-state registers (epilogue role fixed per thread) ----
    const float* bihp = (layer == 0) ? b_ih0 : b_ih + (size_t)(layer - 1) * N3H;
    const float* bhhp = (layer == 0) ? b_hh0 : b_hh + (size_t)(layer - 1) * N3H;
    int jj, eb0;
    float hold0, hold1 = 0.f;
    if (layer == 0) {
        jj = f0 + (tid & 31);
        eb0 = tid >> 5;                     // batch for rep0; rep1 = eb0+16
        hold0 = enc_hidden[(size_t)eb0 * H_ + jj];
        hold1 = enc_hidden[(size_t)(eb0 + 16) * H_ + jj];
    } else {
        jj = f0 + (tid & 15);               // coalesced: 16 consecutive features
        eb0 = tid >> 4;                     // batch
        hold0 = enc_hidden[(size_t)layer * B_ * H_ + (size_t)eb0 * H_ + jj];
    }
    const float bir = bihp[jj], biz = bihp[H_ + jj], bin_ = bihp[2 * H_ + jj];
    const float bhr = bhhp[jj], bhz = bhhp[H_ + jj], bhn = bhhp[2 * H_ + jj];

    const size_t BH = (size_t)B_ * H_;

    for (int c = 0; c < T_ + L_ - 1; ++c) {
        int t = c - layer;
        if (t >= 0 && t < T_) {
            int pw = t & 1, pr = pw ^ 1;
            const unsigned short* hown  = hbf + ((size_t)pr * L_ + layer) * BH;
            const unsigned short* hprev = (layer > 0)
                ? hbf + ((size_t)pw * L_ + (layer - 1)) * BH : nullptr;

            f32x4 acc[3][2];
            #pragma unroll
            for (int i = 0; i < 3; ++i) {
                acc[i][0] = (f32x4){0.f, 0.f, 0.f, 0.f};
                acc[i][1] = (f32x4){0.f, 0.f, 0.f, 0.f};
            }

            const unsigned short* hsrc = (layer == 0 || srcgrp == 1) ? hown : hprev;
            const unsigned short* hp = hsrc + (size_t)rlo * H_ + kc * 256 + klane;
            #pragma unroll
            for (int s = 0; s < 8; ++s) {
                bf16x8 b0 = ld_h16(hp + s * 32);
                bf16x8 b1 = ld_h16(hp + 16 * H_ + s * 32);
                #pragma unroll
                for (int i = 0; i < 3; ++i) {
                    acc[i][0] = __builtin_amdgcn_mfma_f32_16x16x32_bf16(wreg[i][s], b0, acc[i][0], 0, 0, 0);
                    acc[i][1] = __builtin_amdgcn_mfma_f32_16x16x32_bf16(wreg[i][s], b1, acc[i][1], 0, 0, 0);
                }
            }

            #pragma unroll
            for (int i = 0; i < 3; ++i)
                #pragma unroll
                for (int r = 0; r < 4; ++r) {
                    sacc[rgv[i]][kc][rowoff + r][rlo]      = acc[i][0][r];
                    sacc[rgv[i]][kc][rowoff + r][16 + rlo] = acc[i][1][r];
                }
            __syncthreads();

            if (layer > 0) {
                int f = tid & 15, b = tid >> 4;
                float ir = bir, iz = biz, in_ = bin_;
                float hr = bhr, hz = bhz, hn = bhn;
                #pragma unroll
                for (int k2 = 0; k2 < 4; ++k2) {
                    ir += sacc[0][k2][f][b]; iz += sacc[1][k2][f][b]; in_ += sacc[2][k2][f][b];
                    hr += sacc[3][k2][f][b]; hz += sacc[4][k2][f][b]; hn += sacc[5][k2][f][b];
                }
                float r = 1.f / (1.f + expf(-(ir + hr)));
                float z = 1.f / (1.f + expf(-(iz + hz)));
                float n = tanhf(in_ + r * hn);
                float hnew = (1.f - z) * n + z * hold0;
                hold0 = hnew;
                unsigned short hb16 = f2bf(hnew);
                st_h2(&hbf[((size_t)pw * L_ + layer) * BH + (size_t)b * H_ + jj], hb16);
                if (layer == L_ - 1) Hist[((size_t)t * B_ + b) * H_ + jj] = hb16;
                if (t == T_ - 1) hid_out[(size_t)layer * BH + (size_t)b * H_ + jj] = hnew;
            } else {
                int fi = tid & 31;
                int rghalf = fi >> 4, fr = fi & 15;
                {
                    int b = eb0;
                    const unsigned short* g0p = G0 + ((size_t)t * B_ + b) * N3H;
                    float ir = bf2f(g0p[jj]) + bir;
                    float iz = bf2f(g0p[H_ + jj]) + biz;
                    float in_ = bf2f(g0p[2 * H_ + jj]) + bin_;
                    float hr = bhr, hz = bhz, hn = bhn;
                    #pragma unroll
                    for (int k2 = 0; k2 < 4; ++k2) {
                        hr += sacc[rghalf][k2][fr][b];
                        hz += sacc[2 + rghalf][k2][fr][b];
                        hn += sacc[4 + rghalf][k2][fr][b];
                    }
                    float r = 1.f / (1.f + expf(-(ir + hr)));
                    float z = 1.f / (1.f + expf(-(iz + hz)));
                    float n = tanhf(in_ + r * hn);
                    float hnew = (1.f - z) * n + z * hold0;
                    hold0 = hnew;
                    st_h2(&hbf[((size_t)pw * L_) * BH + (size_t)b * H_ + jj], f2bf(hnew));
                    if (t == T_ - 1) hid_out[(size_t)b * H_ + jj] = hnew;
                }
                {
                    int b = eb0 + 16;
                    const unsigned short* g0p = G0 + ((size_t)t * B_ + b) * N3H;
                    float ir = bf2f(g0p[jj]) + bir;
                    float iz = bf2f(g0p[H_ + jj]) + biz;
                    float in_ = bf2f(g0p[2 * H_ + jj]) + bin_;
                    float hr = bhr, hz = bhz, hn = bhn;
                    #pragma unroll
                    for (int k2 = 0; k2 < 4; ++k2) {
                        hr += sacc[rghalf][k2][fr][b];
                        hz += sacc[2 + rghalf][k2][fr][b];
                        hn += sacc[4 + rghalf][k2][fr][b];
                    }
                    float r = 1.f / (1.f + expf(-(ir + hr)));
                    float z = 1.f / (1.f + expf(-(iz + hz)));
                    float n = tanhf(in_ + r * hn);
                    float hnew = (1.f - z) * n + z * hold1;
                    hold1 = hnew;
                    st_h2(&hbf[((size_t)pw * L_) * BH + (size_t)b * H_ + jj], f2bf(hnew));
                    if (t == T_ - 1) hid_out[(size_t)b * H_ + jj] = hnew;
                }
            }
        }
        grid_bar4(flags, (unsigned)(c + 1));
    }
}

// ---------------------------------------------------------------------------
// In-place log_softmax over rows of V_ (float4 vectorized)
// ---------------------------------------------------------------------------
__global__ __launch_bounds__(256) void logsoftmax_kernel(float* __restrict__ dout)
{
    __shared__ float red[256];
    float4* x4 = (float4*)(dout + (size_t)blockIdx.x * V_);
    const int N4 = V_ / 4;
    int tid = threadIdx.x;

    float m = -INFINITY;
    for (int i = tid; i < N4; i += 256) {
        float4 v = x4[i];
        m = fmaxf(m, fmaxf(fmaxf(v.x, v.y), fmaxf(v.z, v.w)));
    }
    red[tid] = m; __syncthreads();
    for (int s = 128; s > 0; s >>= 1) {
        if (tid < s) red[tid] = fmaxf(red[tid], red[tid + s]);
        __syncthreads();
    }
    m = red[0]; __syncthreads();

    float s = 0.f;
    for (int i = tid; i < N4; i += 256) {
        float4 v = x4[i];
        s += expf(v.x - m) + expf(v.y - m) + expf(v.z - m) + expf(v.w - m);
    }
    red[tid] = s; __syncthreads();
    for (int ss = 128; ss > 0; ss >>= 1) {
        if (tid < ss) red[tid] += red[tid + ss];
        __syncthreads();
    }
    float lse = m + logf(red[0]);
    __syncthreads();

    for (int i = tid; i < N4; i += 256) {
        float4 v = x4[i];
        v.x -= lse; v.y -= lse; v.z -= lse; v.w -= lse;
        x4[i] = v;
    }
}

// ---------------------------------------------------------------------------
extern "C" void kernel_launch(void* const* d_in, const int* in_sizes, int n_in,
                              void* d_out, int out_size, void* d_ws, size_t ws_size,
                              hipStream_t stream)
{
    (void)in_sizes; (void)n_in; (void)out_size;

    const float* enc_hidden = (const float*)d_in[1];   // [L][B][H]; layer0 = enc_h
    const int*   target     = (const int*)  d_in[2];
    const float* emb        = (const float*)d_in[3];
    const float* w_ih0      = (const float*)d_in[4];   // [3H][2H]
    const float* w_hh0      = (const float*)d_in[5];   // [3H][H]
    const float* b_ih0      = (const float*)d_in[6];
    const float* b_hh0      = (const float*)d_in[7];
    const float* w_ih       = (const float*)d_in[8];   // [3][3H][H]
    const float* w_hh       = (const float*)d_in[9];
    const float* b_ih       = (const float*)d_in[10];
    const float* b_hh       = (const float*)d_in[11];
    const float* out_w      = (const float*)d_in[12];  // [V][H]
    const float* out_b      = (const float*)d_in[13];
    const float* l1_w       = (const float*)d_in[14];
    const float* l1_b       = (const float*)d_in[15];
    const float* l2_w       = (const float*)d_in[16];
    float* out = (float*)d_out;

    // --- workspace carve ---
    char* w = (char*)d_ws;
    auto alloc = [&](size_t bytes) -> char* {
        char* p = w; w += (bytes + 255) & ~(size_t)255; return p;
    };
    unsigned short* whh0_bf = (unsigned short*)alloc((size_t)N3H * H_ * 2);
    unsigned short* wih_bf  = (unsigned short*)alloc((size_t)3 * N3H * H_ * 2);
    unsigned short* whh_bf  = (unsigned short*)alloc((size_t)3 * N3H * H_ * 2);
    unsigned short* Ebf     = (unsigned short*)alloc((size_t)TB_ * H_ * 2);
    unsigned short* G0      = (unsigned short*)alloc((size_t)TB_ * N3H * 2);
    unsigned short* Hist    = (unsigned short*)alloc((size_t)TB_ * H_ * 2);
    unsigned short* hbf     = (unsigned short*)alloc((size_t)2 * L_ * B_ * H_ * 2);
    float*          Cbuf    = (float*)alloc(H_ * 4);
    float*          scores  = (float*)alloc(256);
    float*          wcC     = (float*)alloc(N3H * 4);
    unsigned*       flags   = (unsigned*)alloc((size_t)NBLK * FSTRIDE * 4);  // 14 KB
    size_t used = (size_t)(w - (char*)d_ws);
    unsigned short* outw_bf = nullptr;
    if (used + (size_t)V_ * H_ * 2 + 256 <= ws_size)
        outw_bf = (unsigned short*)alloc((size_t)V_ * H_ * 2);

    const size_t LBH = (size_t)L_ * B_ * H_;

    hipMemsetAsync(flags, 0, (size_t)NBLK * FSTRIDE * 4, stream);

    // --- one-time precompute ---
    convbf_kernel<<<512, 256, 0, stream>>>(w_hh0, whh0_bf, N3H * H_ / 4);
    convbf_kernel<<<1024, 256, 0, stream>>>(w_ih, wih_bf, 3 * N3H * H_ / 4);
    convbf_kernel<<<1024, 256, 0, stream>>>(w_hh, whh_bf, 3 * N3H * H_ / 4);
    if (outw_bf)
        convbf_kernel<<<2048, 256, 0, stream>>>(out_w, outw_bf, V_ * H_ / 4);
    embed_bf_kernel<<<TB_, 256, 0, stream>>>(target, emb, Ebf);
    convbf_kernel<<<128, 256, 0, stream>>>(enc_hidden, hbf + LBH, (int)(LBH / 4));
    attn_pre_kernel<<<1, 256, 0, stream>>>(enc_hidden, l1_w, l1_b, l2_w, Cbuf, scores);
    wcc_kernel<<<N3H / 4, 256, 0, stream>>>(w_ih0, Cbuf, wcC);
    big_gemm_kernel<<<dim3(N3H / 128, TB_ / 128), 256, 0, stream>>>(
        w_ih0, 2 * H_, 0, Ebf, wcC, N3H, 0, G0);

    // --- persistent pipelined decode (one launch, 103 grid barriers) ---
    decode_kernel<<<NBLK, 512, 0, stream>>>(
        whh0_bf, wih_bf, whh_bf, G0, b_ih0, b_hh0, b_ih, b_hh,
        enc_hidden, hbf, Hist, out + (size_t)B_ * T_ * V_, flags);

    // --- deferred logits GEMM + log_softmax ---
    if (outw_bf)
        big_gemm_kernel<<<dim3(V_ / 128, TB_ / 128), 256, 0, stream>>>(
            outw_bf, H_, 1, Hist, out_b, V_, 1, out);
    else
        big_gemm_kernel<<<dim3(V_ / 128, TB_ / 128), 256, 0, stream>>>(
            out_w, H_, 0, Hist, out_b, V_, 1, out);
    logsoftmax_kernel<<<TB_, 256, 0, stream>>>(out);

    hipMemcpyAsync(out + (size_t)B_ * T_ * V_ + LBH, scores, B_ * 4,
                   hipMemcpyDeviceToDevice, stream);
}